// Round 1
// baseline (1446.058 us; speedup 1.0000x reference)
//
#include <hip/hip_runtime.h>
#include <cstddef>

// CifarNetMem forward: 6x (conv3x3 SAME + bias + relu + LUT-quant), 3x maxpool2x2,
// fc1(2048->512)+reluq, fc2(512->128)+reluq, fc3(128->10)+softmax.
// LUT = linspace(-4,4,129): uniform grid, step 1/16. Nearest w/ tie-to-left:
//   q = 0.0625 * clamp(ceil(16 v - 0.5), -64, 64)
// Quantization applied on-the-fly to weights/biases (on load) and activations (epilogue).

#define B_SZ 512

__device__ __forceinline__ float lutq(float v) {
    float k = ceilf(v * 16.0f - 0.5f);
    k = fminf(64.0f, fmaxf(-64.0f, k));
    return k * 0.0625f;
}

// Direct 3x3 SAME conv + bias + relu + lut-quantize.
// Block = 256 threads. Each thread computes a 2x2 pixel patch for COC output channels.
// NIMG images per block so that NIMG*(HW/2)^2 == 256.
template<int CI, int CO, int HW, int NIMG, int COC, int CIC>
__global__ __launch_bounds__(256) void conv3x3_relu_q(
    const float* __restrict__ in, const float* __restrict__ w,
    const float* __restrict__ bias, float* __restrict__ out)
{
    constexpr int PADW = HW + 2;
    constexpr int HWH  = HW / 2;
    __shared__ float s_in[NIMG][CIC][PADW][PADW];
    __shared__ float s_w[CIC][9][COC];   // tap-major, co contiguous -> ds_read_b128 broadcast

    const int tid = threadIdx.x;
    constexpr int TPI = HWH * HWH;       // threads per image
    const int im  = tid / TPI;
    const int rem = tid % TPI;
    const int py  = (rem / HWH) * 2;
    const int px  = (rem % HWH) * 2;

    const int b0  = blockIdx.x * NIMG;
    const int co0 = blockIdx.y * COC;

    float acc[COC][4];
    #pragma unroll
    for (int o = 0; o < COC; ++o)
        #pragma unroll
        for (int q = 0; q < 4; ++q) acc[o][q] = 0.f;

    for (int ci0 = 0; ci0 < CI; ci0 += CIC) {
        if (ci0) __syncthreads();
        constexpr int TOT = NIMG * CIC * PADW * PADW;
        for (int i = tid; i < TOT; i += 256) {
            int xx = i % PADW;
            int yy = (i / PADW) % PADW;
            int c  = (i / (PADW * PADW)) % CIC;
            int g  = i / (PADW * PADW * CIC);
            int gy = yy - 1, gx = xx - 1;
            float v = 0.f;
            if (gy >= 0 && gy < HW && gx >= 0 && gx < HW)
                v = in[(((size_t)(b0 + g) * CI + ci0 + c) * HW + gy) * HW + gx];
            s_in[g][c][yy][xx] = v;
        }
        constexpr int WTOT = CIC * 9 * COC;
        for (int i = tid; i < WTOT; i += 256) {
            int o = i % COC;
            int k = (i / COC) % 9;
            int c = i / (COC * 9);
            s_w[c][k][o] = lutq(w[((size_t)(co0 + o) * CI + ci0 + c) * 9 + k]);
        }
        __syncthreads();
        #pragma unroll
        for (int c = 0; c < CIC; ++c) {
            #pragma unroll
            for (int k = 0; k < 9; ++k) {
                const int dy = k / 3, dx = k % 3;
                float i00 = s_in[im][c][py + dy][px + dx];
                float i01 = s_in[im][c][py + dy][px + dx + 1];
                float i10 = s_in[im][c][py + 1 + dy][px + dx];
                float i11 = s_in[im][c][py + 1 + dy][px + dx + 1];
                #pragma unroll
                for (int o = 0; o < COC; ++o) {
                    float wv = s_w[c][k][o];
                    acc[o][0] = fmaf(i00, wv, acc[o][0]);
                    acc[o][1] = fmaf(i01, wv, acc[o][1]);
                    acc[o][2] = fmaf(i10, wv, acc[o][2]);
                    acc[o][3] = fmaf(i11, wv, acc[o][3]);
                }
            }
        }
    }

    #pragma unroll
    for (int o = 0; o < COC; ++o) {
        float bb = lutq(bias[co0 + o]);
        size_t base = (((size_t)(b0 + im) * CO + co0 + o) * HW + py) * HW + px;
        out[base]          = lutq(fmaxf(acc[o][0] + bb, 0.f));
        out[base + 1]      = lutq(fmaxf(acc[o][1] + bb, 0.f));
        out[base + HW]     = lutq(fmaxf(acc[o][2] + bb, 0.f));
        out[base + HW + 1] = lutq(fmaxf(acc[o][3] + bb, 0.f));
    }
}

template<int C, int HIN>
__global__ __launch_bounds__(256) void maxpool2x2(
    const float* __restrict__ in, float* __restrict__ out)
{
    constexpr int HO = HIN / 2;
    constexpr int TOTAL = B_SZ * C * HO * HO;
    int idx = blockIdx.x * 256 + threadIdx.x;
    if (idx >= TOTAL) return;
    int x  = idx % HO;
    int y  = (idx / HO) % HO;
    int bc = idx / (HO * HO);
    const float* p = in + ((size_t)bc * HIN + 2 * y) * HIN + 2 * x;
    out[idx] = fmaxf(fmaxf(p[0], p[1]), fmaxf(p[HIN], p[HIN + 1]));
}

// y = x @ Wq^T + bq, optional relu+quant. M=512 rows. 32x32 tile, 2x2 per thread.
template<int N, int K, bool RELUQ>
__global__ __launch_bounds__(256) void fc_kernel(
    const float* __restrict__ x, const float* __restrict__ w,
    const float* __restrict__ bias, float* __restrict__ out)
{
    __shared__ float sx[32][33];
    __shared__ float sw[32][33];
    const int tid = threadIdx.x;
    const int tx = tid % 16, ty = tid / 16;
    const int m0 = blockIdx.x * 32, n0 = blockIdx.y * 32;
    float acc[2][2] = {{0.f, 0.f}, {0.f, 0.f}};

    for (int k0 = 0; k0 < K; k0 += 32) {
        if (k0) __syncthreads();
        for (int i = tid; i < 1024; i += 256) {
            int kk = i % 32, rr = i / 32;
            sx[rr][kk] = x[(size_t)(m0 + rr) * K + k0 + kk];
            sw[rr][kk] = lutq(w[(size_t)(n0 + rr) * K + k0 + kk]);
        }
        __syncthreads();
        #pragma unroll
        for (int kk = 0; kk < 32; ++kk) {
            float x0 = sx[ty][kk],      x1 = sx[ty + 16][kk];
            float w0 = sw[tx][kk],      w1 = sw[tx + 16][kk];
            acc[0][0] = fmaf(x0, w0, acc[0][0]);
            acc[0][1] = fmaf(x0, w1, acc[0][1]);
            acc[1][0] = fmaf(x1, w0, acc[1][0]);
            acc[1][1] = fmaf(x1, w1, acc[1][1]);
        }
    }

    #pragma unroll
    for (int i = 0; i < 2; ++i)
        #pragma unroll
        for (int j = 0; j < 2; ++j) {
            int mm = m0 + ty + i * 16, nn = n0 + tx + j * 16;
            float v = acc[i][j] + lutq(bias[nn]);
            if (RELUQ) v = lutq(fmaxf(v, 0.f));
            out[(size_t)mm * N + nn] = v;
        }
}

// fc3 (128->10) + softmax, one wave per batch row.
__global__ __launch_bounds__(64) void fc3_softmax(
    const float* __restrict__ x, const float* __restrict__ w,
    const float* __restrict__ bias, float* __restrict__ out)
{
    const int r = blockIdx.x;
    const int l = threadIdx.x;
    const float x0 = x[(size_t)r * 128 + l];
    const float x1 = x[(size_t)r * 128 + 64 + l];
    float d[10];
    #pragma unroll
    for (int o = 0; o < 10; ++o) {
        float p = x0 * lutq(w[o * 128 + l]) + x1 * lutq(w[o * 128 + 64 + l]);
        #pragma unroll
        for (int s = 32; s > 0; s >>= 1) p += __shfl_xor(p, s);
        d[o] = p + lutq(bias[o]);
    }
    float m = d[0];
    #pragma unroll
    for (int o = 1; o < 10; ++o) m = fmaxf(m, d[o]);
    float sum = 0.f;
    float e[10];
    #pragma unroll
    for (int o = 0; o < 10; ++o) { e[o] = expf(d[o] - m); sum += e[o]; }
    if (l < 10) {
        float num = 0.f;
        #pragma unroll
        for (int o = 0; o < 10; ++o) if (l == o) num = e[o];
        out[(size_t)r * 10 + l] = num / sum;
    }
}

extern "C" void kernel_launch(void* const* d_in, const int* in_sizes, int n_in,
                              void* d_out, int out_size, void* d_ws, size_t ws_size,
                              hipStream_t stream)
{
    const float* x   = (const float*)d_in[0];
    // d_in[1] = lut (known uniform grid; closed-form quantizer used instead)
    const float* w1  = (const float*)d_in[2];
    const float* b1  = (const float*)d_in[3];
    const float* w2  = (const float*)d_in[4];
    const float* b2  = (const float*)d_in[5];
    const float* w3  = (const float*)d_in[6];
    const float* b3  = (const float*)d_in[7];
    const float* w4  = (const float*)d_in[8];
    const float* b4  = (const float*)d_in[9];
    const float* w5  = (const float*)d_in[10];
    const float* b5  = (const float*)d_in[11];
    const float* w6  = (const float*)d_in[12];
    const float* b6  = (const float*)d_in[13];
    const float* fw1 = (const float*)d_in[14];
    const float* fb1 = (const float*)d_in[15];
    const float* fw2 = (const float*)d_in[16];
    const float* fb2 = (const float*)d_in[17];
    const float* fw3 = (const float*)d_in[18];
    const float* fb3 = (const float*)d_in[19];
    float* out = (float*)d_out;

    // ping-pong activation buffers: 512*32*32*32 floats = 64 MiB each
    float* bufA = (float*)d_ws;
    float* bufB = bufA + (size_t)B_SZ * 32 * 32 * 32;

    dim3 blk(256);

    // conv1: [512,3,32,32] -> [512,32,32,32]
    conv3x3_relu_q<3, 32, 32, 1, 16, 3><<<dim3(512, 2), blk, 0, stream>>>(x, w1, b1, bufA);
    // conv2: -> [512,32,32,32]
    conv3x3_relu_q<32, 32, 32, 1, 16, 4><<<dim3(512, 2), blk, 0, stream>>>(bufA, w2, b2, bufB);
    // pool -> [512,32,16,16]
    maxpool2x2<32, 32><<<dim3((B_SZ * 32 * 16 * 16 + 255) / 256), blk, 0, stream>>>(bufB, bufA);
    // conv3: -> [512,64,16,16]
    conv3x3_relu_q<32, 64, 16, 4, 16, 4><<<dim3(128, 4), blk, 0, stream>>>(bufA, w3, b3, bufB);
    // conv4: -> [512,64,16,16]
    conv3x3_relu_q<64, 64, 16, 4, 16, 4><<<dim3(128, 4), blk, 0, stream>>>(bufB, w4, b4, bufA);
    // pool -> [512,64,8,8]
    maxpool2x2<64, 16><<<dim3((B_SZ * 64 * 8 * 8 + 255) / 256), blk, 0, stream>>>(bufA, bufB);
    // conv5: -> [512,128,8,8]
    conv3x3_relu_q<64, 128, 8, 16, 16, 4><<<dim3(32, 8), blk, 0, stream>>>(bufB, w5, b5, bufA);
    // conv6: -> [512,128,8,8]
    conv3x3_relu_q<128, 128, 8, 16, 16, 4><<<dim3(32, 8), blk, 0, stream>>>(bufA, w6, b6, bufB);
    // pool -> [512,128,4,4] == flattened [512,2048]
    maxpool2x2<128, 8><<<dim3((B_SZ * 128 * 4 * 4 + 255) / 256), blk, 0, stream>>>(bufB, bufA);
    // fc1: [512,2048] -> [512,512], relu+quant
    fc_kernel<512, 2048, true><<<dim3(16, 16), blk, 0, stream>>>(bufA, fw1, fb1, bufB);
    // fc2: [512,512] -> [512,128], relu+quant
    fc_kernel<128, 512, true><<<dim3(16, 4), blk, 0, stream>>>(bufB, fw2, fb2, bufA);
    // fc3 + softmax: [512,128] -> [512,10]
    fc3_softmax<<<dim3(512), dim3(64), 0, stream>>>(bufA, fw3, fb3, out);
}

// Round 2
// 521.249 us; speedup vs baseline: 2.7742x; 2.7742x over previous
//
#include <hip/hip_runtime.h>
#include <cstddef>

// CifarNetMem forward, MFMA path.
// Numerics: lutq values are k/16, |k|<=64 -> exact in bf16; conv/fc sums bounded
// by 2^23 -> fp32 accumulation is EXACT in any order => bf16-MFMA is bit-identical
// to the fp32 reference path for conv2..6 and fc1..3. conv1 stays fp32 (raw input),
// same fma order as previous round -> bit-identical output overall.

#define B_SZ 512
typedef unsigned short u16;
typedef unsigned int   u32;
typedef __attribute__((ext_vector_type(8))) short short8;   // 8 bf16 (4 VGPRs)
typedef __attribute__((ext_vector_type(4))) float f32x4;

__device__ __forceinline__ float lutq(float v) {
    float k = ceilf(v * 16.0f - 0.5f);
    k = fminf(64.0f, fmaxf(-64.0f, k));
    return k * 0.0625f;
}
__device__ __forceinline__ u16  f2b(float f) { return (u16)(__builtin_bit_cast(u32, f) >> 16); }
__device__ __forceinline__ float b2f(u16 u)  { return __builtin_bit_cast(float, (u32)u << 16); }

// ---------------- weight prep: quantize + bf16 + conv-transpose to [co][tap][ci] ----
__global__ __launch_bounds__(256) void prep_weights(
    const float* __restrict__ w2, const float* __restrict__ w3, const float* __restrict__ w4,
    const float* __restrict__ w5, const float* __restrict__ w6,
    const float* __restrict__ fw1, const float* __restrict__ fw2,
    u16* q2, u16* q3, u16* q4, u16* q5, u16* q6, u16* qf1, u16* qf2)
{
    int i = blockIdx.x * 256 + threadIdx.x;
    if (i < 9216) {
        int co = i / 288, r = i % 288, tap = r / 32, ci = r % 32;
        q2[i] = f2b(lutq(w2[(co * 32 + ci) * 9 + tap]));
    } else if ((i -= 9216) < 18432) {
        int co = i / 288, r = i % 288, tap = r / 32, ci = r % 32;
        q3[i] = f2b(lutq(w3[(co * 32 + ci) * 9 + tap]));
    } else if ((i -= 18432) < 36864) {
        int co = i / 576, r = i % 576, tap = r / 64, ci = r % 64;
        q4[i] = f2b(lutq(w4[(co * 64 + ci) * 9 + tap]));
    } else if ((i -= 36864) < 73728) {
        int co = i / 576, r = i % 576, tap = r / 64, ci = r % 64;
        q5[i] = f2b(lutq(w5[(co * 64 + ci) * 9 + tap]));
    } else if ((i -= 73728) < 147456) {
        int co = i / 1152, r = i % 1152, tap = r / 128, ci = r % 128;
        q6[i] = f2b(lutq(w6[(co * 128 + ci) * 9 + tap]));
    } else if ((i -= 147456) < 1048576) {
        qf1[i] = f2b(lutq(fw1[i]));
    } else if ((i -= 1048576) < 65536) {
        qf2[i] = f2b(lutq(fw2[i]));
    }
}

// ---------------- conv1: fp32 (raw input), identical fma order to prev round -------
__global__ __launch_bounds__(256) void conv1_mem(
    const float* __restrict__ x, const float* __restrict__ w,
    const float* __restrict__ bias, u16* __restrict__ out)
{
    __shared__ float s_w[3][9][32];
    __shared__ float s_b[32];
    const int tid = threadIdx.x;
    for (int i = tid; i < 864; i += 256) {
        int o = i % 32, k = (i / 32) % 9, c = i / 288;
        s_w[c][k][o] = lutq(w[(o * 3 + c) * 9 + k]);
    }
    if (tid < 32) s_b[tid] = lutq(bias[tid]);
    __syncthreads();
    const int p = blockIdx.x * 256 + tid;     // b*1024 + y*32 + x
    const int b = p >> 10, y = (p >> 5) & 31, xx = p & 31;
    float acc[32];
    #pragma unroll
    for (int o = 0; o < 32; ++o) acc[o] = 0.f;
    #pragma unroll
    for (int c = 0; c < 3; ++c) {
        #pragma unroll
        for (int k = 0; k < 9; ++k) {
            int gy = y + k / 3 - 1, gx = xx + k % 3 - 1;
            float iv = 0.f;
            if ((unsigned)gy < 32u && (unsigned)gx < 32u)
                iv = x[(((size_t)b * 3 + c) * 32 + gy) * 32 + gx];
            #pragma unroll
            for (int o = 0; o < 32; ++o) acc[o] = fmaf(iv, s_w[c][k][o], acc[o]);
        }
    }
    u32 u[16];
    #pragma unroll
    for (int j = 0; j < 16; ++j) {
        float v0 = lutq(fmaxf(acc[2 * j]     + s_b[2 * j],     0.f));
        float v1 = lutq(fmaxf(acc[2 * j + 1] + s_b[2 * j + 1], 0.f));
        u[j] = (u32)f2b(v0) | ((u32)f2b(v1) << 16);
    }
    u32* o4 = (u32*)(out + (size_t)p * 32);
    #pragma unroll
    for (int j = 0; j < 16; ++j) o4[j] = u[j];
}

// ---------------- MFMA implicit-GEMM conv: NHWC bf16 in/out -------------------------
// Block: NIMG images x RS-row slab => M = NIMG*RS*HW pixels, 4 waves,
// wave = MW m-tiles x NT n-tiles. Input tile staged ONCE (halo'd), XOR-swizzled.
template<int HW, int CI, int CO, int RS, int NIMG, int NT>
__global__ __launch_bounds__(256) void conv_mfma(
    const u16* __restrict__ in,    // [B][HW][HW][CI]
    const u16* __restrict__ wq,    // [CO][9*CI], k = tap*CI+ci
    const float* __restrict__ bias,
    u16* __restrict__ out)         // [B][HW][HW][CO]
{
    constexpr int PH  = HW + 2;
    constexpr int PIX = NIMG * (RS + 2) * PH;
    constexpr int M   = NIMG * RS * HW;
    constexpr int MT  = M / 16;
    constexpr int MW  = MT / 4;
    constexpr int KC  = CI / 32;
    constexpr int SL  = HW / RS;
    constexpr int NC8 = CI / 8;

    __shared__ __align__(128) u16 s_in[PIX * CI];

    const int tid = threadIdx.x;
    const int g   = blockIdx.x;
    const int b0  = (g / SL) * NIMG;
    const int r0  = (g % SL) * RS;
    const int co0 = blockIdx.y * (NT * 16);

    // stage halo'd input tile (16B chunks), swizzled
    constexpr int TOTC = PIX * NC8;
    for (int i = tid; i < TOTC; i += 256) {
        int c8 = i % NC8;
        int pp = i / NC8;
        int xx = pp % PH;
        int rr = pp / PH;
        int yy = rr % (RS + 2);
        int img = rr / (RS + 2);
        int gy = r0 + yy - 1, gx = xx - 1;
        uint4 v = {0u, 0u, 0u, 0u};
        if ((unsigned)gy < (unsigned)HW && (unsigned)gx < (unsigned)HW)
            v = *(const uint4*)(in + ((((size_t)(b0 + img) * HW + gy) * HW + gx) * CI + c8 * 8));
        int off = ((pp * CI + c8 * 8) * 2) ^ ((pp & 7) << 4);
        *(uint4*)((char*)s_in + off) = v;
    }
    __syncthreads();

    const int wv = tid >> 6, ln = tid & 63;
    const int l15 = ln & 15, lq = ln >> 4;

    int ppad[MW];
    #pragma unroll
    for (int mw = 0; mw < MW; ++mw) {
        int p = (wv * MW + mw) * 16 + l15;
        int img = p / (RS * HW);
        int rem = p % (RS * HW);
        int ly = rem / HW, lx = rem % HW;
        ppad[mw] = (img * (RS + 2) + ly + 1) * PH + lx + 1;
    }

    f32x4 acc[MW][NT] = {};

    const u16* wrow[NT];
    #pragma unroll
    for (int nt = 0; nt < NT; ++nt)
        wrow[nt] = wq + (size_t)(co0 + nt * 16 + l15) * (9 * CI) + lq * 8;

    #pragma unroll
    for (int tap = 0; tap < 9; ++tap) {
        const int dy = tap / 3 - 1, dx = tap % 3 - 1;
        #pragma unroll
        for (int cb = 0; cb < KC; ++cb) {
            short8 bf[NT];
            #pragma unroll
            for (int nt = 0; nt < NT; ++nt)
                bf[nt] = *(const short8*)(wrow[nt] + tap * CI + cb * 32);
            #pragma unroll
            for (int mw = 0; mw < MW; ++mw) {
                int pp = ppad[mw] + dy * PH + dx;
                int off = ((pp * CI + cb * 32 + lq * 8) * 2) ^ ((pp & 7) << 4);
                short8 af = *(const short8*)((const char*)s_in + off);
                #pragma unroll
                for (int nt = 0; nt < NT; ++nt)
                    acc[mw][nt] = __builtin_amdgcn_mfma_f32_16x16x32_bf16(
                        af, bf[nt], acc[mw][nt], 0, 0, 0);
            }
        }
    }

    #pragma unroll
    for (int nt = 0; nt < NT; ++nt) {
        float qb = lutq(bias[co0 + nt * 16 + l15]);
        #pragma unroll
        for (int mw = 0; mw < MW; ++mw) {
            #pragma unroll
            for (int r = 0; r < 4; ++r) {
                int p = (wv * MW + mw) * 16 + lq * 4 + r;
                int img = p / (RS * HW), rem = p % (RS * HW);
                int ly = rem / HW, lx = rem % HW;
                float v = lutq(fmaxf(acc[mw][nt][r] + qb, 0.f));
                out[(((size_t)(b0 + img) * HW + r0 + ly) * HW + lx) * CO + co0 + nt * 16 + l15] = f2b(v);
            }
        }
    }
}

// ---------------- maxpool 2x2 on NHWC bf16 ------------------------------------------
__device__ __forceinline__ u32 bmax2(u32 a, u32 b) {
    float m0 = fmaxf(b2f((u16)a), b2f((u16)b));
    float m1 = fmaxf(b2f((u16)(a >> 16)), b2f((u16)(b >> 16)));
    return (u32)f2b(m0) | ((u32)f2b(m1) << 16);
}

template<int C, int HIN>
__global__ __launch_bounds__(256) void pool_nhwc(
    const u16* __restrict__ in, u16* __restrict__ out)
{
    constexpr int HO = HIN / 2, NC8 = C / 8;
    constexpr int TOT = B_SZ * HO * HO * NC8;
    int i = blockIdx.x * 256 + threadIdx.x;
    if (i >= TOT) return;
    int c8 = i % NC8;
    int pp = i / NC8;
    int xo = pp % HO, yo = (pp / HO) % HO, b = pp / (HO * HO);
    const u16* base = in + (size_t)b * HIN * HIN * C + c8 * 8;
    auto ld = [&](int yy, int xxp) {
        return *(const uint4*)(base + ((size_t)yy * HIN + xxp) * C);
    };
    uint4 v0 = ld(2 * yo, 2 * xo), v1 = ld(2 * yo, 2 * xo + 1);
    uint4 v2 = ld(2 * yo + 1, 2 * xo), v3 = ld(2 * yo + 1, 2 * xo + 1);
    uint4 r;
    r.x = bmax2(bmax2(v0.x, v1.x), bmax2(v2.x, v3.x));
    r.y = bmax2(bmax2(v0.y, v1.y), bmax2(v2.y, v3.y));
    r.z = bmax2(bmax2(v0.z, v1.z), bmax2(v2.z, v3.z));
    r.w = bmax2(bmax2(v0.w, v1.w), bmax2(v2.w, v3.w));
    *(uint4*)(out + (((size_t)b * HO + yo) * HO + xo) * C + c8 * 8) = r;
}

// pool3: NHWC [512][8][8][128] -> NCHW-flat [512][2048] (matches reference reshape)
__global__ __launch_bounds__(256) void pool3_flat(
    const u16* __restrict__ in, u16* __restrict__ out)
{
    int i = blockIdx.x * 256 + threadIdx.x;
    if (i >= B_SZ * 2048) return;
    int b = i >> 11, r = i & 2047;
    int c = r >> 4, p = r & 15, yo = p >> 2, xo = p & 3;
    auto at = [&](int dy, int dx) {
        return b2f(in[(((size_t)b * 8 + 2 * yo + dy) * 8 + 2 * xo + dx) * 128 + c]);
    };
    float m = fmaxf(fmaxf(at(0, 0), at(0, 1)), fmaxf(at(1, 0), at(1, 1)));
    out[i] = f2b(m);
}

// ---------------- FC via MFMA, frags straight from global (L2-resident) -------------
template<int N, int K, bool RELUQ>
__global__ __launch_bounds__(256) void fc_mfma(
    const u16* __restrict__ x, const u16* __restrict__ wq,
    const float* __restrict__ bias, u16* __restrict__ out)
{
    const int tid = threadIdx.x, wv = tid >> 6, ln = tid & 63;
    const int l15 = ln & 15, lq = ln >> 4;
    const int m0 = blockIdx.x * 128, n0 = blockIdx.y * 128;
    const int mq = (wv >> 1) * 4, nq = (wv & 1) * 4;
    f32x4 acc[4][4] = {};
    const u16* xr[4];
    const u16* wr[4];
    #pragma unroll
    for (int t = 0; t < 4; ++t) {
        xr[t] = x  + (size_t)(m0 + (mq + t) * 16 + l15) * K + lq * 8;
        wr[t] = wq + (size_t)(n0 + (nq + t) * 16 + l15) * K + lq * 8;
    }
    for (int k0 = 0; k0 < K; k0 += 32) {
        short8 a[4], b[4];
        #pragma unroll
        for (int t = 0; t < 4; ++t) {
            a[t] = *(const short8*)(xr[t] + k0);
            b[t] = *(const short8*)(wr[t] + k0);
        }
        #pragma unroll
        for (int i = 0; i < 4; ++i)
            #pragma unroll
            for (int j = 0; j < 4; ++j)
                acc[i][j] = __builtin_amdgcn_mfma_f32_16x16x32_bf16(a[i], b[j], acc[i][j], 0, 0, 0);
    }
    #pragma unroll
    for (int j = 0; j < 4; ++j) {
        int n = n0 + (nq + j) * 16 + l15;
        float qb = lutq(bias[n]);
        #pragma unroll
        for (int i = 0; i < 4; ++i)
            #pragma unroll
            for (int r = 0; r < 4; ++r) {
                int m = m0 + (mq + i) * 16 + lq * 4 + r;
                float v = acc[i][j][r] + qb;
                if (RELUQ) v = lutq(fmaxf(v, 0.f));
                out[(size_t)m * N + n] = f2b(v);
            }
    }
}

// ---------------- fc3 (128->10) + softmax, one wave per row -------------------------
__global__ __launch_bounds__(64) void fc3_softmax(
    const u16* __restrict__ x, const float* __restrict__ w,
    const float* __restrict__ bias, float* __restrict__ out)
{
    const int r = blockIdx.x;
    const int l = threadIdx.x;
    const float x0 = b2f(x[(size_t)r * 128 + l]);
    const float x1 = b2f(x[(size_t)r * 128 + 64 + l]);
    float d[10];
    #pragma unroll
    for (int o = 0; o < 10; ++o) {
        float p = x0 * lutq(w[o * 128 + l]) + x1 * lutq(w[o * 128 + 64 + l]);
        #pragma unroll
        for (int s = 32; s > 0; s >>= 1) p += __shfl_xor(p, s);
        d[o] = p + lutq(bias[o]);
    }
    float m = d[0];
    #pragma unroll
    for (int o = 1; o < 10; ++o) m = fmaxf(m, d[o]);
    float sum = 0.f;
    float e[10];
    #pragma unroll
    for (int o = 0; o < 10; ++o) { e[o] = expf(d[o] - m); sum += e[o]; }
    if (l < 10) {
        float num = 0.f;
        #pragma unroll
        for (int o = 0; o < 10; ++o) if (l == o) num = e[o];
        out[(size_t)r * 10 + l] = num / sum;
    }
}

extern "C" void kernel_launch(void* const* d_in, const int* in_sizes, int n_in,
                              void* d_out, int out_size, void* d_ws, size_t ws_size,
                              hipStream_t stream)
{
    const float* x   = (const float*)d_in[0];
    const float* w1  = (const float*)d_in[2];
    const float* b1  = (const float*)d_in[3];
    const float* w2  = (const float*)d_in[4];
    const float* b2  = (const float*)d_in[5];
    const float* w3  = (const float*)d_in[6];
    const float* b3  = (const float*)d_in[7];
    const float* w4  = (const float*)d_in[8];
    const float* b4  = (const float*)d_in[9];
    const float* w5  = (const float*)d_in[10];
    const float* b5  = (const float*)d_in[11];
    const float* w6  = (const float*)d_in[12];
    const float* b6  = (const float*)d_in[13];
    const float* fw1 = (const float*)d_in[14];
    const float* fb1 = (const float*)d_in[15];
    const float* fw2 = (const float*)d_in[16];
    const float* fb2 = (const float*)d_in[17];
    const float* fw3 = (const float*)d_in[18];
    const float* fb3 = (const float*)d_in[19];
    float* out = (float*)d_out;

    const size_t ACT = (size_t)B_SZ * 32 * 32 * 32;   // 16,777,216 bf16 elems
    u16* bufA = (u16*)d_ws;
    u16* bufB = bufA + ACT;
    u16* q2  = bufB + ACT;
    u16* q3  = q2 + 9216;
    u16* q4  = q3 + 18432;
    u16* q5  = q4 + 36864;
    u16* q6  = q5 + 73728;
    u16* qf1 = q6 + 147456;
    u16* qf2 = qf1 + (size_t)512 * 2048;

    dim3 blk(256);

    prep_weights<<<dim3((1399808 + 255) / 256), blk, 0, stream>>>(
        w2, w3, w4, w5, w6, fw1, fw2, q2, q3, q4, q5, q6, qf1, qf2);

    // conv1: fp32 -> NHWC bf16 [512,32,32,32]
    conv1_mem<<<dim3(2048), blk, 0, stream>>>(x, w1, b1, bufA);
    // conv2
    conv_mfma<32, 32, 32, 8, 1, 2><<<dim3(2048, 1), blk, 0, stream>>>(bufA, q2, b2, bufB);
    // pool1 -> [512,16,16,32]
    pool_nhwc<32, 32><<<dim3(2048), blk, 0, stream>>>(bufB, bufA);
    // conv3 -> [512,16,16,64]
    conv_mfma<16, 32, 64, 16, 1, 2><<<dim3(512, 2), blk, 0, stream>>>(bufA, q3, b3, bufB);
    // conv4
    conv_mfma<16, 64, 64, 16, 1, 2><<<dim3(512, 2), blk, 0, stream>>>(bufB, q4, b4, bufA);
    // pool2 -> [512,8,8,64]
    pool_nhwc<64, 16><<<dim3(1024), blk, 0, stream>>>(bufA, bufB);
    // conv5 -> [512,8,8,128]
    conv_mfma<8, 64, 128, 8, 2, 4><<<dim3(256, 2), blk, 0, stream>>>(bufB, q5, b5, bufA);
    // conv6
    conv_mfma<8, 128, 128, 8, 2, 4><<<dim3(256, 2), blk, 0, stream>>>(bufA, q6, b6, bufB);
    // pool3 -> NCHW-flat [512,2048]
    pool3_flat<<<dim3(4096), blk, 0, stream>>>(bufB, bufA);
    // fc1 -> [512,512]
    fc_mfma<512, 2048, true><<<dim3(4, 4), blk, 0, stream>>>(bufA, qf1, fb1, bufB);
    // fc2 -> [512,128]
    fc_mfma<128, 512, true><<<dim3(4, 1), blk, 0, stream>>>(bufB, qf2, fb2, bufA);
    // fc3 + softmax
    fc3_softmax<<<dim3(512), dim3(64), 0, stream>>>(bufA, fw3, fb3, out);
}

// Round 3
// 309.289 us; speedup vs baseline: 4.6754x; 1.6853x over previous
//
#include <hip/hip_runtime.h>
#include <cstddef>

// CifarNetMem forward, MFMA path.
// Numerics: lutq values are k/16, |k|<=64 -> exact in bf16; conv/fc sums bounded
// by 2^23 -> fp32 accumulation is EXACT in any order => bf16-MFMA is bit-identical
// to the fp32 reference path for conv2..6 and fc1..3. conv1 stays fp32 (raw input)
// with a FIXED fma order (c outer, k inner) that must not change across rounds.
// R2->R3: conv1 split to 16 output channels/thread (was 32) to kill scratch spills
// (VGPR=256, 1.1 GB of spill traffic). Same fma chain per output => bit-identical.

#define B_SZ 512
typedef unsigned short u16;
typedef unsigned int   u32;
typedef __attribute__((ext_vector_type(8))) short short8;   // 8 bf16 (4 VGPRs)
typedef __attribute__((ext_vector_type(4))) float f32x4;

__device__ __forceinline__ float lutq(float v) {
    float k = ceilf(v * 16.0f - 0.5f);
    k = fminf(64.0f, fmaxf(-64.0f, k));
    return k * 0.0625f;
}
__device__ __forceinline__ u16  f2b(float f) { return (u16)(__builtin_bit_cast(u32, f) >> 16); }
__device__ __forceinline__ float b2f(u16 u)  { return __builtin_bit_cast(float, (u32)u << 16); }

// ---------------- weight prep: quantize + bf16 + conv-transpose to [co][tap][ci] ----
__global__ __launch_bounds__(256) void prep_weights(
    const float* __restrict__ w2, const float* __restrict__ w3, const float* __restrict__ w4,
    const float* __restrict__ w5, const float* __restrict__ w6,
    const float* __restrict__ fw1, const float* __restrict__ fw2,
    u16* q2, u16* q3, u16* q4, u16* q5, u16* q6, u16* qf1, u16* qf2)
{
    int i = blockIdx.x * 256 + threadIdx.x;
    if (i < 9216) {
        int co = i / 288, r = i % 288, tap = r / 32, ci = r % 32;
        q2[i] = f2b(lutq(w2[(co * 32 + ci) * 9 + tap]));
    } else if ((i -= 9216) < 18432) {
        int co = i / 288, r = i % 288, tap = r / 32, ci = r % 32;
        q3[i] = f2b(lutq(w3[(co * 32 + ci) * 9 + tap]));
    } else if ((i -= 18432) < 36864) {
        int co = i / 576, r = i % 576, tap = r / 64, ci = r % 64;
        q4[i] = f2b(lutq(w4[(co * 64 + ci) * 9 + tap]));
    } else if ((i -= 36864) < 73728) {
        int co = i / 576, r = i % 576, tap = r / 64, ci = r % 64;
        q5[i] = f2b(lutq(w5[(co * 64 + ci) * 9 + tap]));
    } else if ((i -= 73728) < 147456) {
        int co = i / 1152, r = i % 1152, tap = r / 128, ci = r % 128;
        q6[i] = f2b(lutq(w6[(co * 128 + ci) * 9 + tap]));
    } else if ((i -= 147456) < 1048576) {
        qf1[i] = f2b(lutq(fw1[i]));
    } else if ((i -= 1048576) < 65536) {
        qf2[i] = f2b(lutq(fw2[i]));
    }
}

// ---------------- conv1: fp32 (raw input), FIXED fma order (c outer, k inner) -------
// 16 output channels per thread (blockIdx.y selects half) to stay spill-free.
__global__ __launch_bounds__(256) void conv1_mem(
    const float* __restrict__ x, const float* __restrict__ w,
    const float* __restrict__ bias, u16* __restrict__ out)
{
    __shared__ float s_w[3][9][16];
    __shared__ float s_b[16];
    const int tid = threadIdx.x;
    const int co0 = blockIdx.y * 16;
    for (int i = tid; i < 432; i += 256) {
        int o = i % 16, k = (i / 16) % 9, c = i / 144;
        s_w[c][k][o] = lutq(w[((co0 + o) * 3 + c) * 9 + k]);
    }
    if (tid < 16) s_b[tid] = lutq(bias[co0 + tid]);
    __syncthreads();
    const int p = blockIdx.x * 256 + tid;     // b*1024 + y*32 + x
    const int b = p >> 10, y = (p >> 5) & 31, xx = p & 31;
    float acc[16];
    #pragma unroll
    for (int o = 0; o < 16; ++o) acc[o] = 0.f;
    #pragma unroll
    for (int c = 0; c < 3; ++c) {
        #pragma unroll
        for (int k = 0; k < 9; ++k) {
            int gy = y + k / 3 - 1, gx = xx + k % 3 - 1;
            float iv = 0.f;
            if ((unsigned)gy < 32u && (unsigned)gx < 32u)
                iv = x[(((size_t)b * 3 + c) * 32 + gy) * 32 + gx];
            #pragma unroll
            for (int o = 0; o < 16; ++o) acc[o] = fmaf(iv, s_w[c][k][o], acc[o]);
        }
    }
    u32 u[8];
    #pragma unroll
    for (int j = 0; j < 8; ++j) {
        float v0 = lutq(fmaxf(acc[2 * j]     + s_b[2 * j],     0.f));
        float v1 = lutq(fmaxf(acc[2 * j + 1] + s_b[2 * j + 1], 0.f));
        u[j] = (u32)f2b(v0) | ((u32)f2b(v1) << 16);
    }
    u32* o4 = (u32*)(out + (size_t)p * 32 + co0);
    #pragma unroll
    for (int j = 0; j < 8; ++j) o4[j] = u[j];
}

// ---------------- MFMA implicit-GEMM conv: NHWC bf16 in/out -------------------------
// Block: NIMG images x RS-row slab => M = NIMG*RS*HW pixels, 4 waves,
// wave = MW m-tiles x NT n-tiles. Input tile staged ONCE (halo'd), XOR-swizzled.
template<int HW, int CI, int CO, int RS, int NIMG, int NT>
__global__ __launch_bounds__(256) void conv_mfma(
    const u16* __restrict__ in,    // [B][HW][HW][CI]
    const u16* __restrict__ wq,    // [CO][9*CI], k = tap*CI+ci
    const float* __restrict__ bias,
    u16* __restrict__ out)         // [B][HW][HW][CO]
{
    constexpr int PH  = HW + 2;
    constexpr int PIX = NIMG * (RS + 2) * PH;
    constexpr int M   = NIMG * RS * HW;
    constexpr int MT  = M / 16;
    constexpr int MW  = MT / 4;
    constexpr int KC  = CI / 32;
    constexpr int SL  = HW / RS;
    constexpr int NC8 = CI / 8;

    __shared__ __align__(128) u16 s_in[PIX * CI];

    const int tid = threadIdx.x;
    const int g   = blockIdx.x;
    const int b0  = (g / SL) * NIMG;
    const int r0  = (g % SL) * RS;
    const int co0 = blockIdx.y * (NT * 16);

    // stage halo'd input tile (16B chunks), swizzled
    constexpr int TOTC = PIX * NC8;
    for (int i = tid; i < TOTC; i += 256) {
        int c8 = i % NC8;
        int pp = i / NC8;
        int xx = pp % PH;
        int rr = pp / PH;
        int yy = rr % (RS + 2);
        int img = rr / (RS + 2);
        int gy = r0 + yy - 1, gx = xx - 1;
        uint4 v = {0u, 0u, 0u, 0u};
        if ((unsigned)gy < (unsigned)HW && (unsigned)gx < (unsigned)HW)
            v = *(const uint4*)(in + ((((size_t)(b0 + img) * HW + gy) * HW + gx) * CI + c8 * 8));
        int off = ((pp * CI + c8 * 8) * 2) ^ ((pp & 7) << 4);
        *(uint4*)((char*)s_in + off) = v;
    }
    __syncthreads();

    const int wv = tid >> 6, ln = tid & 63;
    const int l15 = ln & 15, lq = ln >> 4;

    int ppad[MW];
    #pragma unroll
    for (int mw = 0; mw < MW; ++mw) {
        int p = (wv * MW + mw) * 16 + l15;
        int img = p / (RS * HW);
        int rem = p % (RS * HW);
        int ly = rem / HW, lx = rem % HW;
        ppad[mw] = (img * (RS + 2) + ly + 1) * PH + lx + 1;
    }

    f32x4 acc[MW][NT] = {};

    const u16* wrow[NT];
    #pragma unroll
    for (int nt = 0; nt < NT; ++nt)
        wrow[nt] = wq + (size_t)(co0 + nt * 16 + l15) * (9 * CI) + lq * 8;

    #pragma unroll
    for (int tap = 0; tap < 9; ++tap) {
        const int dy = tap / 3 - 1, dx = tap % 3 - 1;
        #pragma unroll
        for (int cb = 0; cb < KC; ++cb) {
            short8 bf[NT];
            #pragma unroll
            for (int nt = 0; nt < NT; ++nt)
                bf[nt] = *(const short8*)(wrow[nt] + tap * CI + cb * 32);
            #pragma unroll
            for (int mw = 0; mw < MW; ++mw) {
                int pp = ppad[mw] + dy * PH + dx;
                int off = ((pp * CI + cb * 32 + lq * 8) * 2) ^ ((pp & 7) << 4);
                short8 af = *(const short8*)((const char*)s_in + off);
                #pragma unroll
                for (int nt = 0; nt < NT; ++nt)
                    acc[mw][nt] = __builtin_amdgcn_mfma_f32_16x16x32_bf16(
                        af, bf[nt], acc[mw][nt], 0, 0, 0);
            }
        }
    }

    #pragma unroll
    for (int nt = 0; nt < NT; ++nt) {
        float qb = lutq(bias[co0 + nt * 16 + l15]);
        #pragma unroll
        for (int mw = 0; mw < MW; ++mw) {
            #pragma unroll
            for (int r = 0; r < 4; ++r) {
                int p = (wv * MW + mw) * 16 + lq * 4 + r;
                int img = p / (RS * HW), rem = p % (RS * HW);
                int ly = rem / HW, lx = rem % HW;
                float v = lutq(fmaxf(acc[mw][nt][r] + qb, 0.f));
                out[(((size_t)(b0 + img) * HW + r0 + ly) * HW + lx) * CO + co0 + nt * 16 + l15] = f2b(v);
            }
        }
    }
}

// ---------------- maxpool 2x2 on NHWC bf16 ------------------------------------------
__device__ __forceinline__ u32 bmax2(u32 a, u32 b) {
    float m0 = fmaxf(b2f((u16)a), b2f((u16)b));
    float m1 = fmaxf(b2f((u16)(a >> 16)), b2f((u16)(b >> 16)));
    return (u32)f2b(m0) | ((u32)f2b(m1) << 16);
}

template<int C, int HIN>
__global__ __launch_bounds__(256) void pool_nhwc(
    const u16* __restrict__ in, u16* __restrict__ out)
{
    constexpr int HO = HIN / 2, NC8 = C / 8;
    constexpr int TOT = B_SZ * HO * HO * NC8;
    int i = blockIdx.x * 256 + threadIdx.x;
    if (i >= TOT) return;
    int c8 = i % NC8;
    int pp = i / NC8;
    int xo = pp % HO, yo = (pp / HO) % HO, b = pp / (HO * HO);
    const u16* base = in + (size_t)b * HIN * HIN * C + c8 * 8;
    auto ld = [&](int yy, int xxp) {
        return *(const uint4*)(base + ((size_t)yy * HIN + xxp) * C);
    };
    uint4 v0 = ld(2 * yo, 2 * xo), v1 = ld(2 * yo, 2 * xo + 1);
    uint4 v2 = ld(2 * yo + 1, 2 * xo), v3 = ld(2 * yo + 1, 2 * xo + 1);
    uint4 r;
    r.x = bmax2(bmax2(v0.x, v1.x), bmax2(v2.x, v3.x));
    r.y = bmax2(bmax2(v0.y, v1.y), bmax2(v2.y, v3.y));
    r.z = bmax2(bmax2(v0.z, v1.z), bmax2(v2.z, v3.z));
    r.w = bmax2(bmax2(v0.w, v1.w), bmax2(v2.w, v3.w));
    *(uint4*)(out + (((size_t)b * HO + yo) * HO + xo) * C + c8 * 8) = r;
}

// pool3: NHWC [512][8][8][128] -> NCHW-flat [512][2048] (matches reference reshape)
__global__ __launch_bounds__(256) void pool3_flat(
    const u16* __restrict__ in, u16* __restrict__ out)
{
    int i = blockIdx.x * 256 + threadIdx.x;
    if (i >= B_SZ * 2048) return;
    int b = i >> 11, r = i & 2047;
    int c = r >> 4, p = r & 15, yo = p >> 2, xo = p & 3;
    auto at = [&](int dy, int dx) {
        return b2f(in[(((size_t)b * 8 + 2 * yo + dy) * 8 + 2 * xo + dx) * 128 + c]);
    };
    float m = fmaxf(fmaxf(at(0, 0), at(0, 1)), fmaxf(at(1, 0), at(1, 1)));
    out[i] = f2b(m);
}

// ---------------- FC via MFMA, frags straight from global (L2-resident) -------------
template<int N, int K, bool RELUQ>
__global__ __launch_bounds__(256) void fc_mfma(
    const u16* __restrict__ x, const u16* __restrict__ wq,
    const float* __restrict__ bias, u16* __restrict__ out)
{
    const int tid = threadIdx.x, wv = tid >> 6, ln = tid & 63;
    const int l15 = ln & 15, lq = ln >> 4;
    const int m0 = blockIdx.x * 128, n0 = blockIdx.y * 128;
    const int mq = (wv >> 1) * 4, nq = (wv & 1) * 4;
    f32x4 acc[4][4] = {};
    const u16* xr[4];
    const u16* wr[4];
    #pragma unroll
    for (int t = 0; t < 4; ++t) {
        xr[t] = x  + (size_t)(m0 + (mq + t) * 16 + l15) * K + lq * 8;
        wr[t] = wq + (size_t)(n0 + (nq + t) * 16 + l15) * K + lq * 8;
    }
    for (int k0 = 0; k0 < K; k0 += 32) {
        short8 a[4], b[4];
        #pragma unroll
        for (int t = 0; t < 4; ++t) {
            a[t] = *(const short8*)(xr[t] + k0);
            b[t] = *(const short8*)(wr[t] + k0);
        }
        #pragma unroll
        for (int i = 0; i < 4; ++i)
            #pragma unroll
            for (int j = 0; j < 4; ++j)
                acc[i][j] = __builtin_amdgcn_mfma_f32_16x16x32_bf16(a[i], b[j], acc[i][j], 0, 0, 0);
    }
    #pragma unroll
    for (int j = 0; j < 4; ++j) {
        int n = n0 + (nq + j) * 16 + l15;
        float qb = lutq(bias[n]);
        #pragma unroll
        for (int i = 0; i < 4; ++i)
            #pragma unroll
            for (int r = 0; r < 4; ++r) {
                int m = m0 + (mq + i) * 16 + lq * 4 + r;
                float v = acc[i][j][r] + qb;
                if (RELUQ) v = lutq(fmaxf(v, 0.f));
                out[(size_t)m * N + n] = f2b(v);
            }
    }
}

// ---------------- fc3 (128->10) + softmax, one wave per row -------------------------
__global__ __launch_bounds__(64) void fc3_softmax(
    const u16* __restrict__ x, const float* __restrict__ w,
    const float* __restrict__ bias, float* __restrict__ out)
{
    const int r = blockIdx.x;
    const int l = threadIdx.x;
    const float x0 = b2f(x[(size_t)r * 128 + l]);
    const float x1 = b2f(x[(size_t)r * 128 + 64 + l]);
    float d[10];
    #pragma unroll
    for (int o = 0; o < 10; ++o) {
        float p = x0 * lutq(w[o * 128 + l]) + x1 * lutq(w[o * 128 + 64 + l]);
        #pragma unroll
        for (int s = 32; s > 0; s >>= 1) p += __shfl_xor(p, s);
        d[o] = p + lutq(bias[o]);
    }
    float m = d[0];
    #pragma unroll
    for (int o = 1; o < 10; ++o) m = fmaxf(m, d[o]);
    float sum = 0.f;
    float e[10];
    #pragma unroll
    for (int o = 0; o < 10; ++o) { e[o] = expf(d[o] - m); sum += e[o]; }
    if (l < 10) {
        float num = 0.f;
        #pragma unroll
        for (int o = 0; o < 10; ++o) if (l == o) num = e[o];
        out[(size_t)r * 10 + l] = num / sum;
    }
}

extern "C" void kernel_launch(void* const* d_in, const int* in_sizes, int n_in,
                              void* d_out, int out_size, void* d_ws, size_t ws_size,
                              hipStream_t stream)
{
    const float* x   = (const float*)d_in[0];
    const float* w1  = (const float*)d_in[2];
    const float* b1  = (const float*)d_in[3];
    const float* w2  = (const float*)d_in[4];
    const float* b2  = (const float*)d_in[5];
    const float* w3  = (const float*)d_in[6];
    const float* b3  = (const float*)d_in[7];
    const float* w4  = (const float*)d_in[8];
    const float* b4  = (const float*)d_in[9];
    const float* w5  = (const float*)d_in[10];
    const float* b5  = (const float*)d_in[11];
    const float* w6  = (const float*)d_in[12];
    const float* b6  = (const float*)d_in[13];
    const float* fw1 = (const float*)d_in[14];
    const float* fb1 = (const float*)d_in[15];
    const float* fw2 = (const float*)d_in[16];
    const float* fb2 = (const float*)d_in[17];
    const float* fw3 = (const float*)d_in[18];
    const float* fb3 = (const float*)d_in[19];
    float* out = (float*)d_out;

    const size_t ACT = (size_t)B_SZ * 32 * 32 * 32;   // 16,777,216 bf16 elems
    u16* bufA = (u16*)d_ws;
    u16* bufB = bufA + ACT;
    u16* q2  = bufB + ACT;
    u16* q3  = q2 + 9216;
    u16* q4  = q3 + 18432;
    u16* q5  = q4 + 36864;
    u16* q6  = q5 + 73728;
    u16* qf1 = q6 + 147456;
    u16* qf2 = qf1 + (size_t)512 * 2048;

    dim3 blk(256);

    prep_weights<<<dim3((1399808 + 255) / 256), blk, 0, stream>>>(
        w2, w3, w4, w5, w6, fw1, fw2, q2, q3, q4, q5, q6, qf1, qf2);

    // conv1: fp32 -> NHWC bf16 [512,32,32,32]; y-dim splits output channels 2x16
    conv1_mem<<<dim3(2048, 2), blk, 0, stream>>>(x, w1, b1, bufA);
    // conv2
    conv_mfma<32, 32, 32, 8, 1, 2><<<dim3(2048, 1), blk, 0, stream>>>(bufA, q2, b2, bufB);
    // pool1 -> [512,16,16,32]
    pool_nhwc<32, 32><<<dim3(2048), blk, 0, stream>>>(bufB, bufA);
    // conv3 -> [512,16,16,64]
    conv_mfma<16, 32, 64, 16, 1, 2><<<dim3(512, 2), blk, 0, stream>>>(bufA, q3, b3, bufB);
    // conv4
    conv_mfma<16, 64, 64, 16, 1, 2><<<dim3(512, 2), blk, 0, stream>>>(bufB, q4, b4, bufA);
    // pool2 -> [512,8,8,64]
    pool_nhwc<64, 16><<<dim3(1024), blk, 0, stream>>>(bufA, bufB);
    // conv5 -> [512,8,8,128]
    conv_mfma<8, 64, 128, 8, 2, 4><<<dim3(256, 2), blk, 0, stream>>>(bufB, q5, b5, bufA);
    // conv6
    conv_mfma<8, 128, 128, 8, 2, 4><<<dim3(256, 2), blk, 0, stream>>>(bufA, q6, b6, bufB);
    // pool3 -> NCHW-flat [512,2048]
    pool3_flat<<<dim3(4096), blk, 0, stream>>>(bufB, bufA);
    // fc1 -> [512,512]
    fc_mfma<512, 2048, true><<<dim3(4, 4), blk, 0, stream>>>(bufA, qf1, fb1, bufB);
    // fc2 -> [512,128]
    fc_mfma<128, 512, true><<<dim3(4, 1), blk, 0, stream>>>(bufB, qf2, fb2, bufA);
    // fc3 + softmax
    fc3_softmax<<<dim3(512), dim3(64), 0, stream>>>(bufA, fw3, fb3, out);
}

// Round 4
// 244.240 us; speedup vs baseline: 5.9206x; 1.2663x over previous
//
#include <hip/hip_runtime.h>
#include <cstddef>

// CifarNetMem forward, MFMA path.
// Numerics: lutq values are k/16, |k|<=64 -> exact in bf16; conv/fc sums bounded
// by 2^23 -> fp32 accumulation is EXACT in any order => bf16-MFMA is bit-identical
// to the fp32 reference path for conv2..6 and fc1..3. conv1 stays fp32 (raw input)
// with a FIXED fma order (c outer, k inner) that must not change across rounds.
// R3->R4: fc1/fc2 were latency-bound (16/4 blocks, 0.68% occupancy, 67 us each).
// Split-K (grid z) with fp32 partials + reduce epilogue: exact => bit-identical.

#define B_SZ 512
typedef unsigned short u16;
typedef unsigned int   u32;
typedef __attribute__((ext_vector_type(8))) short short8;   // 8 bf16 (4 VGPRs)
typedef __attribute__((ext_vector_type(4))) float f32x4;

__device__ __forceinline__ float lutq(float v) {
    float k = ceilf(v * 16.0f - 0.5f);
    k = fminf(64.0f, fmaxf(-64.0f, k));
    return k * 0.0625f;
}
__device__ __forceinline__ u16  f2b(float f) { return (u16)(__builtin_bit_cast(u32, f) >> 16); }
__device__ __forceinline__ float b2f(u16 u)  { return __builtin_bit_cast(float, (u32)u << 16); }

// ---------------- weight prep: quantize + bf16 + conv-transpose to [co][tap][ci] ----
__global__ __launch_bounds__(256) void prep_weights(
    const float* __restrict__ w2, const float* __restrict__ w3, const float* __restrict__ w4,
    const float* __restrict__ w5, const float* __restrict__ w6,
    const float* __restrict__ fw1, const float* __restrict__ fw2,
    u16* q2, u16* q3, u16* q4, u16* q5, u16* q6, u16* qf1, u16* qf2)
{
    int i = blockIdx.x * 256 + threadIdx.x;
    if (i < 9216) {
        int co = i / 288, r = i % 288, tap = r / 32, ci = r % 32;
        q2[i] = f2b(lutq(w2[(co * 32 + ci) * 9 + tap]));
    } else if ((i -= 9216) < 18432) {
        int co = i / 288, r = i % 288, tap = r / 32, ci = r % 32;
        q3[i] = f2b(lutq(w3[(co * 32 + ci) * 9 + tap]));
    } else if ((i -= 18432) < 36864) {
        int co = i / 576, r = i % 576, tap = r / 64, ci = r % 64;
        q4[i] = f2b(lutq(w4[(co * 64 + ci) * 9 + tap]));
    } else if ((i -= 36864) < 73728) {
        int co = i / 576, r = i % 576, tap = r / 64, ci = r % 64;
        q5[i] = f2b(lutq(w5[(co * 64 + ci) * 9 + tap]));
    } else if ((i -= 73728) < 147456) {
        int co = i / 1152, r = i % 1152, tap = r / 128, ci = r % 128;
        q6[i] = f2b(lutq(w6[(co * 128 + ci) * 9 + tap]));
    } else if ((i -= 147456) < 1048576) {
        qf1[i] = f2b(lutq(fw1[i]));
    } else if ((i -= 1048576) < 65536) {
        qf2[i] = f2b(lutq(fw2[i]));
    }
}

// ---------------- conv1: fp32 (raw input), FIXED fma order (c outer, k inner) -------
__global__ __launch_bounds__(256) void conv1_mem(
    const float* __restrict__ x, const float* __restrict__ w,
    const float* __restrict__ bias, u16* __restrict__ out)
{
    __shared__ float s_w[3][9][16];
    __shared__ float s_b[16];
    const int tid = threadIdx.x;
    const int co0 = blockIdx.y * 16;
    for (int i = tid; i < 432; i += 256) {
        int o = i % 16, k = (i / 16) % 9, c = i / 144;
        s_w[c][k][o] = lutq(w[((co0 + o) * 3 + c) * 9 + k]);
    }
    if (tid < 16) s_b[tid] = lutq(bias[co0 + tid]);
    __syncthreads();
    const int p = blockIdx.x * 256 + tid;     // b*1024 + y*32 + x
    const int b = p >> 10, y = (p >> 5) & 31, xx = p & 31;
    float acc[16];
    #pragma unroll
    for (int o = 0; o < 16; ++o) acc[o] = 0.f;
    #pragma unroll
    for (int c = 0; c < 3; ++c) {
        #pragma unroll
        for (int k = 0; k < 9; ++k) {
            int gy = y + k / 3 - 1, gx = xx + k % 3 - 1;
            float iv = 0.f;
            if ((unsigned)gy < 32u && (unsigned)gx < 32u)
                iv = x[(((size_t)b * 3 + c) * 32 + gy) * 32 + gx];
            #pragma unroll
            for (int o = 0; o < 16; ++o) acc[o] = fmaf(iv, s_w[c][k][o], acc[o]);
        }
    }
    u32 u[8];
    #pragma unroll
    for (int j = 0; j < 8; ++j) {
        float v0 = lutq(fmaxf(acc[2 * j]     + s_b[2 * j],     0.f));
        float v1 = lutq(fmaxf(acc[2 * j + 1] + s_b[2 * j + 1], 0.f));
        u[j] = (u32)f2b(v0) | ((u32)f2b(v1) << 16);
    }
    u32* o4 = (u32*)(out + (size_t)p * 32 + co0);
    #pragma unroll
    for (int j = 0; j < 8; ++j) o4[j] = u[j];
}

// ---------------- MFMA implicit-GEMM conv: NHWC bf16 in/out -------------------------
template<int HW, int CI, int CO, int RS, int NIMG, int NT>
__global__ __launch_bounds__(256) void conv_mfma(
    const u16* __restrict__ in,    // [B][HW][HW][CI]
    const u16* __restrict__ wq,    // [CO][9*CI], k = tap*CI+ci
    const float* __restrict__ bias,
    u16* __restrict__ out)         // [B][HW][HW][CO]
{
    constexpr int PH  = HW + 2;
    constexpr int PIX = NIMG * (RS + 2) * PH;
    constexpr int M   = NIMG * RS * HW;
    constexpr int MT  = M / 16;
    constexpr int MW  = MT / 4;
    constexpr int KC  = CI / 32;
    constexpr int SL  = HW / RS;
    constexpr int NC8 = CI / 8;

    __shared__ __align__(128) u16 s_in[PIX * CI];

    const int tid = threadIdx.x;
    const int g   = blockIdx.x;
    const int b0  = (g / SL) * NIMG;
    const int r0  = (g % SL) * RS;
    const int co0 = blockIdx.y * (NT * 16);

    constexpr int TOTC = PIX * NC8;
    for (int i = tid; i < TOTC; i += 256) {
        int c8 = i % NC8;
        int pp = i / NC8;
        int xx = pp % PH;
        int rr = pp / PH;
        int yy = rr % (RS + 2);
        int img = rr / (RS + 2);
        int gy = r0 + yy - 1, gx = xx - 1;
        uint4 v = {0u, 0u, 0u, 0u};
        if ((unsigned)gy < (unsigned)HW && (unsigned)gx < (unsigned)HW)
            v = *(const uint4*)(in + ((((size_t)(b0 + img) * HW + gy) * HW + gx) * CI + c8 * 8));
        int off = ((pp * CI + c8 * 8) * 2) ^ ((pp & 7) << 4);
        *(uint4*)((char*)s_in + off) = v;
    }
    __syncthreads();

    const int wv = tid >> 6, ln = tid & 63;
    const int l15 = ln & 15, lq = ln >> 4;

    int ppad[MW];
    #pragma unroll
    for (int mw = 0; mw < MW; ++mw) {
        int p = (wv * MW + mw) * 16 + l15;
        int img = p / (RS * HW);
        int rem = p % (RS * HW);
        int ly = rem / HW, lx = rem % HW;
        ppad[mw] = (img * (RS + 2) + ly + 1) * PH + lx + 1;
    }

    f32x4 acc[MW][NT] = {};

    const u16* wrow[NT];
    #pragma unroll
    for (int nt = 0; nt < NT; ++nt)
        wrow[nt] = wq + (size_t)(co0 + nt * 16 + l15) * (9 * CI) + lq * 8;

    #pragma unroll
    for (int tap = 0; tap < 9; ++tap) {
        const int dy = tap / 3 - 1, dx = tap % 3 - 1;
        #pragma unroll
        for (int cb = 0; cb < KC; ++cb) {
            short8 bf[NT];
            #pragma unroll
            for (int nt = 0; nt < NT; ++nt)
                bf[nt] = *(const short8*)(wrow[nt] + tap * CI + cb * 32);
            #pragma unroll
            for (int mw = 0; mw < MW; ++mw) {
                int pp = ppad[mw] + dy * PH + dx;
                int off = ((pp * CI + cb * 32 + lq * 8) * 2) ^ ((pp & 7) << 4);
                short8 af = *(const short8*)((const char*)s_in + off);
                #pragma unroll
                for (int nt = 0; nt < NT; ++nt)
                    acc[mw][nt] = __builtin_amdgcn_mfma_f32_16x16x32_bf16(
                        af, bf[nt], acc[mw][nt], 0, 0, 0);
            }
        }
    }

    #pragma unroll
    for (int nt = 0; nt < NT; ++nt) {
        float qb = lutq(bias[co0 + nt * 16 + l15]);
        #pragma unroll
        for (int mw = 0; mw < MW; ++mw) {
            #pragma unroll
            for (int r = 0; r < 4; ++r) {
                int p = (wv * MW + mw) * 16 + lq * 4 + r;
                int img = p / (RS * HW), rem = p % (RS * HW);
                int ly = rem / HW, lx = rem % HW;
                float v = lutq(fmaxf(acc[mw][nt][r] + qb, 0.f));
                out[(((size_t)(b0 + img) * HW + r0 + ly) * HW + lx) * CO + co0 + nt * 16 + l15] = f2b(v);
            }
        }
    }
}

// ---------------- maxpool 2x2 on NHWC bf16 ------------------------------------------
__device__ __forceinline__ u32 bmax2(u32 a, u32 b) {
    float m0 = fmaxf(b2f((u16)a), b2f((u16)b));
    float m1 = fmaxf(b2f((u16)(a >> 16)), b2f((u16)(b >> 16)));
    return (u32)f2b(m0) | ((u32)f2b(m1) << 16);
}

template<int C, int HIN>
__global__ __launch_bounds__(256) void pool_nhwc(
    const u16* __restrict__ in, u16* __restrict__ out)
{
    constexpr int HO = HIN / 2, NC8 = C / 8;
    constexpr int TOT = B_SZ * HO * HO * NC8;
    int i = blockIdx.x * 256 + threadIdx.x;
    if (i >= TOT) return;
    int c8 = i % NC8;
    int pp = i / NC8;
    int xo = pp % HO, yo = (pp / HO) % HO, b = pp / (HO * HO);
    const u16* base = in + (size_t)b * HIN * HIN * C + c8 * 8;
    auto ld = [&](int yy, int xxp) {
        return *(const uint4*)(base + ((size_t)yy * HIN + xxp) * C);
    };
    uint4 v0 = ld(2 * yo, 2 * xo), v1 = ld(2 * yo, 2 * xo + 1);
    uint4 v2 = ld(2 * yo + 1, 2 * xo), v3 = ld(2 * yo + 1, 2 * xo + 1);
    uint4 r;
    r.x = bmax2(bmax2(v0.x, v1.x), bmax2(v2.x, v3.x));
    r.y = bmax2(bmax2(v0.y, v1.y), bmax2(v2.y, v3.y));
    r.z = bmax2(bmax2(v0.z, v1.z), bmax2(v2.z, v3.z));
    r.w = bmax2(bmax2(v0.w, v1.w), bmax2(v2.w, v3.w));
    *(uint4*)(out + (((size_t)b * HO + yo) * HO + xo) * C + c8 * 8) = r;
}

// pool3: NHWC [512][8][8][128] -> NCHW-flat [512][2048] (matches reference reshape)
__global__ __launch_bounds__(256) void pool3_flat(
    const u16* __restrict__ in, u16* __restrict__ out)
{
    int i = blockIdx.x * 256 + threadIdx.x;
    if (i >= B_SZ * 2048) return;
    int b = i >> 11, r = i & 2047;
    int c = r >> 4, p = r & 15, yo = p >> 2, xo = p & 3;
    auto at = [&](int dy, int dx) {
        return b2f(in[(((size_t)b * 8 + 2 * yo + dy) * 8 + 2 * xo + dx) * 128 + c]);
    };
    float m = fmaxf(fmaxf(at(0, 0), at(0, 1)), fmaxf(at(1, 0), at(1, 1)));
    out[i] = f2b(m);
}

// ---------------- FC via MFMA, split-K: partials fp32 (exact) -----------------------
// grid (M/128, N/128, SK). Each block: 128x128 tile over K-chunk K/SK.
template<int N, int K, int SK>
__global__ __launch_bounds__(256) void fc_splitk(
    const u16* __restrict__ x, const u16* __restrict__ wq, float* __restrict__ part)
{
    constexpr int KCH = K / SK;
    const int tid = threadIdx.x, wv = tid >> 6, ln = tid & 63;
    const int l15 = ln & 15, lq = ln >> 4;
    const int m0 = blockIdx.x * 128, n0 = blockIdx.y * 128;
    const int kb = blockIdx.z * KCH;
    const int mq = (wv >> 1) * 4, nq = (wv & 1) * 4;
    f32x4 acc[4][4] = {};
    const u16* xr[4];
    const u16* wr[4];
    #pragma unroll
    for (int t = 0; t < 4; ++t) {
        xr[t] = x  + (size_t)(m0 + (mq + t) * 16 + l15) * K + kb + lq * 8;
        wr[t] = wq + (size_t)(n0 + (nq + t) * 16 + l15) * K + kb + lq * 8;
    }
    for (int k0 = 0; k0 < KCH; k0 += 32) {
        short8 a[4], b[4];
        #pragma unroll
        for (int t = 0; t < 4; ++t) {
            a[t] = *(const short8*)(xr[t] + k0);
            b[t] = *(const short8*)(wr[t] + k0);
        }
        #pragma unroll
        for (int i = 0; i < 4; ++i)
            #pragma unroll
            for (int j = 0; j < 4; ++j)
                acc[i][j] = __builtin_amdgcn_mfma_f32_16x16x32_bf16(a[i], b[j], acc[i][j], 0, 0, 0);
    }
    float* pb = part + (size_t)blockIdx.z * (B_SZ * N);
    #pragma unroll
    for (int j = 0; j < 4; ++j) {
        int n = n0 + (nq + j) * 16 + l15;
        #pragma unroll
        for (int i = 0; i < 4; ++i)
            #pragma unroll
            for (int r = 0; r < 4; ++r) {
                int m = m0 + (mq + i) * 16 + lq * 4 + r;
                pb[(size_t)m * N + n] = acc[i][j][r];
            }
    }
}

// reduce SK partials + bias (+reluq) -> bf16
template<int N, int SK, bool RELUQ>
__global__ __launch_bounds__(256) void fc_reduce(
    const float* __restrict__ part, const float* __restrict__ bias, u16* __restrict__ out)
{
    int i = blockIdx.x * 256 + threadIdx.x;
    if (i >= B_SZ * N) return;
    float s = 0.f;
    #pragma unroll
    for (int k = 0; k < SK; ++k) s += part[(size_t)k * (B_SZ * N) + i];
    float v = s + lutq(bias[i % N]);
    if (RELUQ) v = lutq(fmaxf(v, 0.f));
    out[i] = f2b(v);
}

// ---------------- fc3 (128->10) + softmax, one wave per row -------------------------
__global__ __launch_bounds__(64) void fc3_softmax(
    const u16* __restrict__ x, const float* __restrict__ w,
    const float* __restrict__ bias, float* __restrict__ out)
{
    const int r = blockIdx.x;
    const int l = threadIdx.x;
    const float x0 = b2f(x[(size_t)r * 128 + l]);
    const float x1 = b2f(x[(size_t)r * 128 + 64 + l]);
    float d[10];
    #pragma unroll
    for (int o = 0; o < 10; ++o) {
        float p = x0 * lutq(w[o * 128 + l]) + x1 * lutq(w[o * 128 + 64 + l]);
        #pragma unroll
        for (int s = 32; s > 0; s >>= 1) p += __shfl_xor(p, s);
        d[o] = p + lutq(bias[o]);
    }
    float m = d[0];
    #pragma unroll
    for (int o = 1; o < 10; ++o) m = fmaxf(m, d[o]);
    float sum = 0.f;
    float e[10];
    #pragma unroll
    for (int o = 0; o < 10; ++o) { e[o] = expf(d[o] - m); sum += e[o]; }
    if (l < 10) {
        float num = 0.f;
        #pragma unroll
        for (int o = 0; o < 10; ++o) if (l == o) num = e[o];
        out[(size_t)r * 10 + l] = num / sum;
    }
}

extern "C" void kernel_launch(void* const* d_in, const int* in_sizes, int n_in,
                              void* d_out, int out_size, void* d_ws, size_t ws_size,
                              hipStream_t stream)
{
    const float* x   = (const float*)d_in[0];
    const float* w1  = (const float*)d_in[2];
    const float* b1  = (const float*)d_in[3];
    const float* w2  = (const float*)d_in[4];
    const float* b2  = (const float*)d_in[5];
    const float* w3  = (const float*)d_in[6];
    const float* b3  = (const float*)d_in[7];
    const float* w4  = (const float*)d_in[8];
    const float* b4  = (const float*)d_in[9];
    const float* w5  = (const float*)d_in[10];
    const float* b5  = (const float*)d_in[11];
    const float* w6  = (const float*)d_in[12];
    const float* b6  = (const float*)d_in[13];
    const float* fw1 = (const float*)d_in[14];
    const float* fb1 = (const float*)d_in[15];
    const float* fw2 = (const float*)d_in[16];
    const float* fb2 = (const float*)d_in[17];
    const float* fw3 = (const float*)d_in[18];
    const float* fb3 = (const float*)d_in[19];
    float* out = (float*)d_out;

    const size_t ACT = (size_t)B_SZ * 32 * 32 * 32;   // 16,777,216 bf16 elems
    u16* bufA = (u16*)d_ws;
    u16* bufB = bufA + ACT;
    u16* q2  = bufB + ACT;
    u16* q3  = q2 + 9216;
    u16* q4  = q3 + 18432;
    u16* q5  = q4 + 36864;
    u16* q6  = q5 + 73728;
    u16* qf1 = q6 + 147456;
    u16* qf2 = qf1 + (size_t)512 * 2048;
    u16* fc1out = bufA + (2u << 20);          // past fc1 input (512*2048 elems)

    dim3 blk(256);

    prep_weights<<<dim3((1399808 + 255) / 256), blk, 0, stream>>>(
        w2, w3, w4, w5, w6, fw1, fw2, q2, q3, q4, q5, q6, qf1, qf2);

    // conv1: fp32 -> NHWC bf16 [512,32,32,32]; y-dim splits output channels 2x16
    conv1_mem<<<dim3(2048, 2), blk, 0, stream>>>(x, w1, b1, bufA);
    // conv2
    conv_mfma<32, 32, 32, 8, 1, 2><<<dim3(2048, 1), blk, 0, stream>>>(bufA, q2, b2, bufB);
    // pool1 -> [512,16,16,32]
    pool_nhwc<32, 32><<<dim3(2048), blk, 0, stream>>>(bufB, bufA);
    // conv3 -> [512,16,16,64]
    conv_mfma<16, 32, 64, 16, 1, 2><<<dim3(512, 2), blk, 0, stream>>>(bufA, q3, b3, bufB);
    // conv4
    conv_mfma<16, 64, 64, 16, 1, 2><<<dim3(512, 2), blk, 0, stream>>>(bufB, q4, b4, bufA);
    // pool2 -> [512,8,8,64]
    pool_nhwc<64, 16><<<dim3(1024), blk, 0, stream>>>(bufA, bufB);
    // conv5 -> [512,8,8,128]
    conv_mfma<8, 64, 128, 8, 2, 4><<<dim3(256, 2), blk, 0, stream>>>(bufB, q5, b5, bufA);
    // conv6
    conv_mfma<8, 128, 128, 8, 2, 4><<<dim3(256, 2), blk, 0, stream>>>(bufA, q6, b6, bufB);
    // pool3 -> NCHW-flat [512,2048] into bufA
    pool3_flat<<<dim3(4096), blk, 0, stream>>>(bufB, bufA);

    // fc1: [512,2048]->[512,512] split-K=16, partials fp32 in bufB (16 MB), exact
    fc_splitk<512, 2048, 16><<<dim3(4, 4, 16), blk, 0, stream>>>(bufA, qf1, (float*)bufB);
    fc_reduce<512, 16, true><<<dim3(1024), blk, 0, stream>>>((float*)bufB, fb1, fc1out);
    // fc2: [512,512]->[512,128] split-K=16 (1 iter/block), partials 1 MB
    fc_splitk<128, 512, 16><<<dim3(4, 1, 16), blk, 0, stream>>>(fc1out, qf2, (float*)bufB);
    fc_reduce<128, 16, true><<<dim3(256), blk, 0, stream>>>((float*)bufB, fb2, bufA);
    // fc3 + softmax
    fc3_softmax<<<dim3(512), dim3(64), 0, stream>>>(bufA, fw3, fb3, out);
}

// Round 5
// 210.553 us; speedup vs baseline: 6.8679x; 1.1600x over previous
//
#include <hip/hip_runtime.h>
#include <cstddef>

// CifarNetMem forward, MFMA path.
// Numerics: lutq values are k/16, |k|<=64 -> exact in bf16; conv/fc sums bounded
// by 2^23 -> fp32 accumulation is EXACT in any order => bf16-MFMA is bit-identical
// to the fp32 reference path for conv2..6 and fc1..3. conv1 stays fp32 (raw input)
// with a FIXED fma order (c outer, k inner) that must not change across rounds.
// R4->R5: conv1 was latency-bound (VGPR=228 from 27 hoisted bounds-checked global
// loads, 9.3% occupancy). Input quarter-tile staged to LDS (3x10x34 halo'd, zeros
// baked in) -> same values, same fma order => bit-identical, but spill-free and
// LDS-latency loads.

#define B_SZ 512
typedef unsigned short u16;
typedef unsigned int   u32;
typedef __attribute__((ext_vector_type(8))) short short8;   // 8 bf16 (4 VGPRs)
typedef __attribute__((ext_vector_type(4))) float f32x4;

__device__ __forceinline__ float lutq(float v) {
    float k = ceilf(v * 16.0f - 0.5f);
    k = fminf(64.0f, fmaxf(-64.0f, k));
    return k * 0.0625f;
}
__device__ __forceinline__ u16  f2b(float f) { return (u16)(__builtin_bit_cast(u32, f) >> 16); }
__device__ __forceinline__ float b2f(u16 u)  { return __builtin_bit_cast(float, (u32)u << 16); }

// ---------------- weight prep: quantize + bf16 + conv-transpose to [co][tap][ci] ----
__global__ __launch_bounds__(256) void prep_weights(
    const float* __restrict__ w2, const float* __restrict__ w3, const float* __restrict__ w4,
    const float* __restrict__ w5, const float* __restrict__ w6,
    const float* __restrict__ fw1, const float* __restrict__ fw2,
    u16* q2, u16* q3, u16* q4, u16* q5, u16* q6, u16* qf1, u16* qf2)
{
    int i = blockIdx.x * 256 + threadIdx.x;
    if (i < 9216) {
        int co = i / 288, r = i % 288, tap = r / 32, ci = r % 32;
        q2[i] = f2b(lutq(w2[(co * 32 + ci) * 9 + tap]));
    } else if ((i -= 9216) < 18432) {
        int co = i / 288, r = i % 288, tap = r / 32, ci = r % 32;
        q3[i] = f2b(lutq(w3[(co * 32 + ci) * 9 + tap]));
    } else if ((i -= 18432) < 36864) {
        int co = i / 576, r = i % 576, tap = r / 64, ci = r % 64;
        q4[i] = f2b(lutq(w4[(co * 64 + ci) * 9 + tap]));
    } else if ((i -= 36864) < 73728) {
        int co = i / 576, r = i % 576, tap = r / 64, ci = r % 64;
        q5[i] = f2b(lutq(w5[(co * 64 + ci) * 9 + tap]));
    } else if ((i -= 73728) < 147456) {
        int co = i / 1152, r = i % 1152, tap = r / 128, ci = r % 128;
        q6[i] = f2b(lutq(w6[(co * 128 + ci) * 9 + tap]));
    } else if ((i -= 147456) < 1048576) {
        qf1[i] = f2b(lutq(fw1[i]));
    } else if ((i -= 1048576) < 65536) {
        qf2[i] = f2b(lutq(fw2[i]));
    }
}

// ---------------- conv1: fp32 (raw input), FIXED fma order (c outer, k inner) -------
// Quarter-image tile staged to LDS with halo; 16 output channels per block-y.
__global__ __launch_bounds__(256) void conv1_mem(
    const float* __restrict__ x, const float* __restrict__ w,
    const float* __restrict__ bias, u16* __restrict__ out)
{
    __shared__ float s_w[3][9][16];
    __shared__ float s_b[16];
    __shared__ float s_in[3][10][34];
    const int tid = threadIdx.x;
    const int co0 = blockIdx.y * 16;
    const int b   = blockIdx.x >> 2;          // image
    const int r0  = (blockIdx.x & 3) * 8;     // row quarter
    for (int i = tid; i < 432; i += 256) {
        int o = i % 16, k = (i / 16) % 9, c = i / 144;
        s_w[c][k][o] = lutq(w[((co0 + o) * 3 + c) * 9 + k]);
    }
    if (tid < 16) s_b[tid] = lutq(bias[co0 + tid]);
    for (int i = tid; i < 3 * 10 * 34; i += 256) {
        int xx = i % 34, yy = (i / 34) % 10, c = i / 340;
        int gy = r0 + yy - 1, gx = xx - 1;
        float v = 0.f;
        if ((unsigned)gy < 32u && (unsigned)gx < 32u)
            v = x[(((size_t)b * 3 + c) * 32 + gy) * 32 + gx];
        s_in[c][yy][xx] = v;
    }
    __syncthreads();
    const int y = tid >> 5, xx = tid & 31;    // local row 0..7, col 0..31
    float acc[16];
    #pragma unroll
    for (int o = 0; o < 16; ++o) acc[o] = 0.f;
    #pragma unroll
    for (int c = 0; c < 3; ++c) {
        #pragma unroll
        for (int k = 0; k < 9; ++k) {
            float iv = s_in[c][y + k / 3][xx + k % 3];
            #pragma unroll
            for (int o = 0; o < 16; ++o) acc[o] = fmaf(iv, s_w[c][k][o], acc[o]);
        }
    }
    u32 u[8];
    #pragma unroll
    for (int j = 0; j < 8; ++j) {
        float v0 = lutq(fmaxf(acc[2 * j]     + s_b[2 * j],     0.f));
        float v1 = lutq(fmaxf(acc[2 * j + 1] + s_b[2 * j + 1], 0.f));
        u[j] = (u32)f2b(v0) | ((u32)f2b(v1) << 16);
    }
    const int p = (b << 10) + ((r0 + y) << 5) + xx;   // b*1024 + row*32 + col
    u32* o4 = (u32*)(out + (size_t)p * 32 + co0);
    #pragma unroll
    for (int j = 0; j < 8; ++j) o4[j] = u[j];
}

// ---------------- MFMA implicit-GEMM conv: NHWC bf16 in/out -------------------------
template<int HW, int CI, int CO, int RS, int NIMG, int NT>
__global__ __launch_bounds__(256) void conv_mfma(
    const u16* __restrict__ in,    // [B][HW][HW][CI]
    const u16* __restrict__ wq,    // [CO][9*CI], k = tap*CI+ci
    const float* __restrict__ bias,
    u16* __restrict__ out)         // [B][HW][HW][CO]
{
    constexpr int PH  = HW + 2;
    constexpr int PIX = NIMG * (RS + 2) * PH;
    constexpr int M   = NIMG * RS * HW;
    constexpr int MT  = M / 16;
    constexpr int MW  = MT / 4;
    constexpr int KC  = CI / 32;
    constexpr int SL  = HW / RS;
    constexpr int NC8 = CI / 8;

    __shared__ __align__(128) u16 s_in[PIX * CI];

    const int tid = threadIdx.x;
    const int g   = blockIdx.x;
    const int b0  = (g / SL) * NIMG;
    const int r0  = (g % SL) * RS;
    const int co0 = blockIdx.y * (NT * 16);

    constexpr int TOTC = PIX * NC8;
    for (int i = tid; i < TOTC; i += 256) {
        int c8 = i % NC8;
        int pp = i / NC8;
        int xx = pp % PH;
        int rr = pp / PH;
        int yy = rr % (RS + 2);
        int img = rr / (RS + 2);
        int gy = r0 + yy - 1, gx = xx - 1;
        uint4 v = {0u, 0u, 0u, 0u};
        if ((unsigned)gy < (unsigned)HW && (unsigned)gx < (unsigned)HW)
            v = *(const uint4*)(in + ((((size_t)(b0 + img) * HW + gy) * HW + gx) * CI + c8 * 8));
        int off = ((pp * CI + c8 * 8) * 2) ^ ((pp & 7) << 4);
        *(uint4*)((char*)s_in + off) = v;
    }
    __syncthreads();

    const int wv = tid >> 6, ln = tid & 63;
    const int l15 = ln & 15, lq = ln >> 4;

    int ppad[MW];
    #pragma unroll
    for (int mw = 0; mw < MW; ++mw) {
        int p = (wv * MW + mw) * 16 + l15;
        int img = p / (RS * HW);
        int rem = p % (RS * HW);
        int ly = rem / HW, lx = rem % HW;
        ppad[mw] = (img * (RS + 2) + ly + 1) * PH + lx + 1;
    }

    f32x4 acc[MW][NT] = {};

    const u16* wrow[NT];
    #pragma unroll
    for (int nt = 0; nt < NT; ++nt)
        wrow[nt] = wq + (size_t)(co0 + nt * 16 + l15) * (9 * CI) + lq * 8;

    #pragma unroll
    for (int tap = 0; tap < 9; ++tap) {
        const int dy = tap / 3 - 1, dx = tap % 3 - 1;
        #pragma unroll
        for (int cb = 0; cb < KC; ++cb) {
            short8 bf[NT];
            #pragma unroll
            for (int nt = 0; nt < NT; ++nt)
                bf[nt] = *(const short8*)(wrow[nt] + tap * CI + cb * 32);
            #pragma unroll
            for (int mw = 0; mw < MW; ++mw) {
                int pp = ppad[mw] + dy * PH + dx;
                int off = ((pp * CI + cb * 32 + lq * 8) * 2) ^ ((pp & 7) << 4);
                short8 af = *(const short8*)((const char*)s_in + off);
                #pragma unroll
                for (int nt = 0; nt < NT; ++nt)
                    acc[mw][nt] = __builtin_amdgcn_mfma_f32_16x16x32_bf16(
                        af, bf[nt], acc[mw][nt], 0, 0, 0);
            }
        }
    }

    #pragma unroll
    for (int nt = 0; nt < NT; ++nt) {
        float qb = lutq(bias[co0 + nt * 16 + l15]);
        #pragma unroll
        for (int mw = 0; mw < MW; ++mw) {
            #pragma unroll
            for (int r = 0; r < 4; ++r) {
                int p = (wv * MW + mw) * 16 + lq * 4 + r;
                int img = p / (RS * HW), rem = p % (RS * HW);
                int ly = rem / HW, lx = rem % HW;
                float v = lutq(fmaxf(acc[mw][nt][r] + qb, 0.f));
                out[(((size_t)(b0 + img) * HW + r0 + ly) * HW + lx) * CO + co0 + nt * 16 + l15] = f2b(v);
            }
        }
    }
}

// ---------------- maxpool 2x2 on NHWC bf16 ------------------------------------------
__device__ __forceinline__ u32 bmax2(u32 a, u32 b) {
    float m0 = fmaxf(b2f((u16)a), b2f((u16)b));
    float m1 = fmaxf(b2f((u16)(a >> 16)), b2f((u16)(b >> 16)));
    return (u32)f2b(m0) | ((u32)f2b(m1) << 16);
}

template<int C, int HIN>
__global__ __launch_bounds__(256) void pool_nhwc(
    const u16* __restrict__ in, u16* __restrict__ out)
{
    constexpr int HO = HIN / 2, NC8 = C / 8;
    constexpr int TOT = B_SZ * HO * HO * NC8;
    int i = blockIdx.x * 256 + threadIdx.x;
    if (i >= TOT) return;
    int c8 = i % NC8;
    int pp = i / NC8;
    int xo = pp % HO, yo = (pp / HO) % HO, b = pp / (HO * HO);
    const u16* base = in + (size_t)b * HIN * HIN * C + c8 * 8;
    auto ld = [&](int yy, int xxp) {
        return *(const uint4*)(base + ((size_t)yy * HIN + xxp) * C);
    };
    uint4 v0 = ld(2 * yo, 2 * xo), v1 = ld(2 * yo, 2 * xo + 1);
    uint4 v2 = ld(2 * yo + 1, 2 * xo), v3 = ld(2 * yo + 1, 2 * xo + 1);
    uint4 r;
    r.x = bmax2(bmax2(v0.x, v1.x), bmax2(v2.x, v3.x));
    r.y = bmax2(bmax2(v0.y, v1.y), bmax2(v2.y, v3.y));
    r.z = bmax2(bmax2(v0.z, v1.z), bmax2(v2.z, v3.z));
    r.w = bmax2(bmax2(v0.w, v1.w), bmax2(v2.w, v3.w));
    *(uint4*)(out + (((size_t)b * HO + yo) * HO + xo) * C + c8 * 8) = r;
}

// pool3: NHWC [512][8][8][128] -> NCHW-flat [512][2048] (matches reference reshape)
__global__ __launch_bounds__(256) void pool3_flat(
    const u16* __restrict__ in, u16* __restrict__ out)
{
    int i = blockIdx.x * 256 + threadIdx.x;
    if (i >= B_SZ * 2048) return;
    int b = i >> 11, r = i & 2047;
    int c = r >> 4, p = r & 15, yo = p >> 2, xo = p & 3;
    auto at = [&](int dy, int dx) {
        return b2f(in[(((size_t)b * 8 + 2 * yo + dy) * 8 + 2 * xo + dx) * 128 + c]);
    };
    float m = fmaxf(fmaxf(at(0, 0), at(0, 1)), fmaxf(at(1, 0), at(1, 1)));
    out[i] = f2b(m);
}

// ---------------- FC via MFMA, split-K: partials fp32 (exact) -----------------------
template<int N, int K, int SK>
__global__ __launch_bounds__(256) void fc_splitk(
    const u16* __restrict__ x, const u16* __restrict__ wq, float* __restrict__ part)
{
    constexpr int KCH = K / SK;
    const int tid = threadIdx.x, wv = tid >> 6, ln = tid & 63;
    const int l15 = ln & 15, lq = ln >> 4;
    const int m0 = blockIdx.x * 128, n0 = blockIdx.y * 128;
    const int kb = blockIdx.z * KCH;
    const int mq = (wv >> 1) * 4, nq = (wv & 1) * 4;
    f32x4 acc[4][4] = {};
    const u16* xr[4];
    const u16* wr[4];
    #pragma unroll
    for (int t = 0; t < 4; ++t) {
        xr[t] = x  + (size_t)(m0 + (mq + t) * 16 + l15) * K + kb + lq * 8;
        wr[t] = wq + (size_t)(n0 + (nq + t) * 16 + l15) * K + kb + lq * 8;
    }
    for (int k0 = 0; k0 < KCH; k0 += 32) {
        short8 a[4], b[4];
        #pragma unroll
        for (int t = 0; t < 4; ++t) {
            a[t] = *(const short8*)(xr[t] + k0);
            b[t] = *(const short8*)(wr[t] + k0);
        }
        #pragma unroll
        for (int i = 0; i < 4; ++i)
            #pragma unroll
            for (int j = 0; j < 4; ++j)
                acc[i][j] = __builtin_amdgcn_mfma_f32_16x16x32_bf16(a[i], b[j], acc[i][j], 0, 0, 0);
    }
    float* pb = part + (size_t)blockIdx.z * (B_SZ * N);
    #pragma unroll
    for (int j = 0; j < 4; ++j) {
        int n = n0 + (nq + j) * 16 + l15;
        #pragma unroll
        for (int i = 0; i < 4; ++i)
            #pragma unroll
            for (int r = 0; r < 4; ++r) {
                int m = m0 + (mq + i) * 16 + lq * 4 + r;
                pb[(size_t)m * N + n] = acc[i][j][r];
            }
    }
}

// reduce SK partials + bias (+reluq) -> bf16
template<int N, int SK, bool RELUQ>
__global__ __launch_bounds__(256) void fc_reduce(
    const float* __restrict__ part, const float* __restrict__ bias, u16* __restrict__ out)
{
    int i = blockIdx.x * 256 + threadIdx.x;
    if (i >= B_SZ * N) return;
    float s = 0.f;
    #pragma unroll
    for (int k = 0; k < SK; ++k) s += part[(size_t)k * (B_SZ * N) + i];
    float v = s + lutq(bias[i % N]);
    if (RELUQ) v = lutq(fmaxf(v, 0.f));
    out[i] = f2b(v);
}

// ---------------- fc3 (128->10) + softmax, one wave per row -------------------------
__global__ __launch_bounds__(64) void fc3_softmax(
    const u16* __restrict__ x, const float* __restrict__ w,
    const float* __restrict__ bias, float* __restrict__ out)
{
    const int r = blockIdx.x;
    const int l = threadIdx.x;
    const float x0 = b2f(x[(size_t)r * 128 + l]);
    const float x1 = b2f(x[(size_t)r * 128 + 64 + l]);
    float d[10];
    #pragma unroll
    for (int o = 0; o < 10; ++o) {
        float p = x0 * lutq(w[o * 128 + l]) + x1 * lutq(w[o * 128 + 64 + l]);
        #pragma unroll
        for (int s = 32; s > 0; s >>= 1) p += __shfl_xor(p, s);
        d[o] = p + lutq(bias[o]);
    }
    float m = d[0];
    #pragma unroll
    for (int o = 1; o < 10; ++o) m = fmaxf(m, d[o]);
    float sum = 0.f;
    float e[10];
    #pragma unroll
    for (int o = 0; o < 10; ++o) { e[o] = expf(d[o] - m); sum += e[o]; }
    if (l < 10) {
        float num = 0.f;
        #pragma unroll
        for (int o = 0; o < 10; ++o) if (l == o) num = e[o];
        out[(size_t)r * 10 + l] = num / sum;
    }
}

extern "C" void kernel_launch(void* const* d_in, const int* in_sizes, int n_in,
                              void* d_out, int out_size, void* d_ws, size_t ws_size,
                              hipStream_t stream)
{
    const float* x   = (const float*)d_in[0];
    const float* w1  = (const float*)d_in[2];
    const float* b1  = (const float*)d_in[3];
    const float* w2  = (const float*)d_in[4];
    const float* b2  = (const float*)d_in[5];
    const float* w3  = (const float*)d_in[6];
    const float* b3  = (const float*)d_in[7];
    const float* w4  = (const float*)d_in[8];
    const float* b4  = (const float*)d_in[9];
    const float* w5  = (const float*)d_in[10];
    const float* b5  = (const float*)d_in[11];
    const float* w6  = (const float*)d_in[12];
    const float* b6  = (const float*)d_in[13];
    const float* fw1 = (const float*)d_in[14];
    const float* fb1 = (const float*)d_in[15];
    const float* fw2 = (const float*)d_in[16];
    const float* fb2 = (const float*)d_in[17];
    const float* fw3 = (const float*)d_in[18];
    const float* fb3 = (const float*)d_in[19];
    float* out = (float*)d_out;

    const size_t ACT = (size_t)B_SZ * 32 * 32 * 32;   // 16,777,216 bf16 elems
    u16* bufA = (u16*)d_ws;
    u16* bufB = bufA + ACT;
    u16* q2  = bufB + ACT;
    u16* q3  = q2 + 9216;
    u16* q4  = q3 + 18432;
    u16* q5  = q4 + 36864;
    u16* q6  = q5 + 73728;
    u16* qf1 = q6 + 147456;
    u16* qf2 = qf1 + (size_t)512 * 2048;
    u16* fc1out = bufA + (2u << 20);          // past fc1 input (512*2048 elems)

    dim3 blk(256);

    prep_weights<<<dim3((1399808 + 255) / 256), blk, 0, stream>>>(
        w2, w3, w4, w5, w6, fw1, fw2, q2, q3, q4, q5, q6, qf1, qf2);

    // conv1: fp32 -> NHWC bf16 [512,32,32,32]; x = img*4+quarter, y = co half
    conv1_mem<<<dim3(2048, 2), blk, 0, stream>>>(x, w1, b1, bufA);
    // conv2
    conv_mfma<32, 32, 32, 8, 1, 2><<<dim3(2048, 1), blk, 0, stream>>>(bufA, q2, b2, bufB);
    // pool1 -> [512,16,16,32]
    pool_nhwc<32, 32><<<dim3(2048), blk, 0, stream>>>(bufB, bufA);
    // conv3 -> [512,16,16,64]
    conv_mfma<16, 32, 64, 16, 1, 2><<<dim3(512, 2), blk, 0, stream>>>(bufA, q3, b3, bufB);
    // conv4
    conv_mfma<16, 64, 64, 16, 1, 2><<<dim3(512, 2), blk, 0, stream>>>(bufB, q4, b4, bufA);
    // pool2 -> [512,8,8,64]
    pool_nhwc<64, 16><<<dim3(1024), blk, 0, stream>>>(bufA, bufB);
    // conv5 -> [512,8,8,128]
    conv_mfma<8, 64, 128, 8, 2, 4><<<dim3(256, 2), blk, 0, stream>>>(bufB, q5, b5, bufA);
    // conv6
    conv_mfma<8, 128, 128, 8, 2, 4><<<dim3(256, 2), blk, 0, stream>>>(bufA, q6, b6, bufB);
    // pool3 -> NCHW-flat [512,2048] into bufA
    pool3_flat<<<dim3(4096), blk, 0, stream>>>(bufB, bufA);

    // fc1: [512,2048]->[512,512] split-K=16, partials fp32 in bufB (16 MB), exact
    fc_splitk<512, 2048, 16><<<dim3(4, 4, 16), blk, 0, stream>>>(bufA, qf1, (float*)bufB);
    fc_reduce<512, 16, true><<<dim3(1024), blk, 0, stream>>>((float*)bufB, fb1, fc1out);
    // fc2: [512,512]->[512,128] split-K=16 (1 iter/block), partials 1 MB
    fc_splitk<128, 512, 16><<<dim3(4, 1, 16), blk, 0, stream>>>(fc1out, qf2, (float*)bufB);
    fc_reduce<128, 16, true><<<dim3(256), blk, 0, stream>>>((float*)bufB, fb2, bufA);
    // fc3 + softmax
    fc3_softmax<<<dim3(512), dim3(64), 0, stream>>>(bufA, fw3, fb3, out);
}

// Round 6
// 165.597 us; speedup vs baseline: 8.7324x; 1.2715x over previous
//
#include <hip/hip_runtime.h>
#include <cstddef>

// CifarNetMem forward, MFMA path.
// Numerics: lutq values are k/16, |k|<=64 -> exact in bf16; conv/fc sums bounded
// by 2^23 -> fp32 accumulation is EXACT in any order => bf16-MFMA is bit-identical
// to the fp32 reference path for conv2..6 and fc1..3. conv1 stays fp32 (raw input)
// with a FIXED fma order (c outer, k inner) that must not change across rounds.
// R5->R6: conv/fc B-operand loads were 16-way scattered (per-lane co-row addresses,
// 16 cache lines per instruction; L1 thrash). Weights now stored in MFMA FRAGMENT
// ORDER: per (co-tile, 32k-step) a 1KB block where lane ln reads base+ln*16B ->
// every B load is one coalesced segment. Pure layout change => bit-identical.

#define B_SZ 512
typedef unsigned short u16;
typedef unsigned int   u32;
typedef __attribute__((ext_vector_type(8))) short short8;   // 8 bf16 (4 VGPRs)
typedef __attribute__((ext_vector_type(4))) float f32x4;

__device__ __forceinline__ float lutq(float v) {
    float k = ceilf(v * 16.0f - 0.5f);
    k = fminf(64.0f, fmaxf(-64.0f, k));
    return k * 0.0625f;
}
__device__ __forceinline__ u16  f2b(float f) { return (u16)(__builtin_bit_cast(u32, f) >> 16); }
__device__ __forceinline__ float b2f(u16 u)  { return __builtin_bit_cast(float, (u32)u << 16); }

// ---------------- weight prep: quantize + bf16 + MFMA-fragment order ----------------
// conv frag layout: i = ((co_tile*NSTEP + step)*64 + ln)*8 + e, step = tap*KC + cb,
//   lane ln=(lq*16+l15) holds w[co_tile*16+l15][ci = cb*32+lq*8+e][tap]  (OIHW src)
__device__ __forceinline__ void prep_conv_frag(const float* __restrict__ w, u16* __restrict__ q,
                                               int i, int CI) {
    int KC = CI >> 5, NSTEP = 9 * KC;
    int e = i & 7, t = i >> 3;
    int ln = t & 63, t2 = t >> 6;
    int step = t2 % NSTEP, co_tile = t2 / NSTEP;
    int tap = step / KC, cb = step - tap * KC;
    int co = co_tile * 16 + (ln & 15);
    int ci = cb * 32 + (ln >> 4) * 8 + e;
    q[i] = f2b(lutq(w[(co * CI + ci) * 9 + tap]));
}
// fc frag layout: i = ((n_tile*(K/32) + s)*64 + ln)*8 + e -> w[n_tile*16+l15][s*32+lq*8+e]
__device__ __forceinline__ void prep_fc_frag(const float* __restrict__ w, u16* __restrict__ q,
                                             int i, int K) {
    int S = K >> 5;
    int e = i & 7, t = i >> 3;
    int ln = t & 63, t2 = t >> 6;
    int s = t2 % S, n_tile = t2 / S;
    int n = n_tile * 16 + (ln & 15);
    int k = s * 32 + (ln >> 4) * 8 + e;
    q[i] = f2b(lutq(w[(size_t)n * K + k]));
}

__global__ __launch_bounds__(256) void prep_weights(
    const float* __restrict__ w2, const float* __restrict__ w3, const float* __restrict__ w4,
    const float* __restrict__ w5, const float* __restrict__ w6,
    const float* __restrict__ fw1, const float* __restrict__ fw2,
    u16* q2, u16* q3, u16* q4, u16* q5, u16* q6, u16* qf1, u16* qf2)
{
    int i = blockIdx.x * 256 + threadIdx.x;
    if (i < 9216)                 { prep_conv_frag(w2, q2, i, 32);  }
    else if ((i -= 9216) < 18432) { prep_conv_frag(w3, q3, i, 32);  }
    else if ((i -= 18432) < 36864){ prep_conv_frag(w4, q4, i, 64);  }
    else if ((i -= 36864) < 73728){ prep_conv_frag(w5, q5, i, 64);  }
    else if ((i -= 73728) < 147456){ prep_conv_frag(w6, q6, i, 128); }
    else if ((i -= 147456) < 1048576){ prep_fc_frag(fw1, qf1, i, 2048); }
    else if ((i -= 1048576) < 65536) { prep_fc_frag(fw2, qf2, i, 512);  }
}

// ---------------- conv1: fp32 (raw input), FIXED fma order (c outer, k inner) -------
__global__ __launch_bounds__(256) void conv1_mem(
    const float* __restrict__ x, const float* __restrict__ w,
    const float* __restrict__ bias, u16* __restrict__ out)
{
    __shared__ float s_w[3][9][16];
    __shared__ float s_b[16];
    __shared__ float s_in[3][10][34];
    const int tid = threadIdx.x;
    const int co0 = blockIdx.y * 16;
    const int b   = blockIdx.x >> 2;          // image
    const int r0  = (blockIdx.x & 3) * 8;     // row quarter
    for (int i = tid; i < 432; i += 256) {
        int o = i % 16, k = (i / 16) % 9, c = i / 144;
        s_w[c][k][o] = lutq(w[((co0 + o) * 3 + c) * 9 + k]);
    }
    if (tid < 16) s_b[tid] = lutq(bias[co0 + tid]);
    for (int i = tid; i < 3 * 10 * 34; i += 256) {
        int xx = i % 34, yy = (i / 34) % 10, c = i / 340;
        int gy = r0 + yy - 1, gx = xx - 1;
        float v = 0.f;
        if ((unsigned)gy < 32u && (unsigned)gx < 32u)
            v = x[(((size_t)b * 3 + c) * 32 + gy) * 32 + gx];
        s_in[c][yy][xx] = v;
    }
    __syncthreads();
    const int y = tid >> 5, xx = tid & 31;    // local row 0..7, col 0..31
    float acc[16];
    #pragma unroll
    for (int o = 0; o < 16; ++o) acc[o] = 0.f;
    #pragma unroll
    for (int c = 0; c < 3; ++c) {
        #pragma unroll
        for (int k = 0; k < 9; ++k) {
            float iv = s_in[c][y + k / 3][xx + k % 3];
            #pragma unroll
            for (int o = 0; o < 16; ++o) acc[o] = fmaf(iv, s_w[c][k][o], acc[o]);
        }
    }
    u32 u[8];
    #pragma unroll
    for (int j = 0; j < 8; ++j) {
        float v0 = lutq(fmaxf(acc[2 * j]     + s_b[2 * j],     0.f));
        float v1 = lutq(fmaxf(acc[2 * j + 1] + s_b[2 * j + 1], 0.f));
        u[j] = (u32)f2b(v0) | ((u32)f2b(v1) << 16);
    }
    const int p = (b << 10) + ((r0 + y) << 5) + xx;   // b*1024 + row*32 + col
    u32* o4 = (u32*)(out + (size_t)p * 32 + co0);
    #pragma unroll
    for (int j = 0; j < 8; ++j) o4[j] = u[j];
}

// ---------------- MFMA implicit-GEMM conv: NHWC bf16 in/out -------------------------
template<int HW, int CI, int CO, int RS, int NIMG, int NT>
__global__ __launch_bounds__(256) void conv_mfma(
    const u16* __restrict__ in,    // [B][HW][HW][CI]
    const u16* __restrict__ wq,    // fragment-ordered (see prep)
    const float* __restrict__ bias,
    u16* __restrict__ out)         // [B][HW][HW][CO]
{
    constexpr int PH  = HW + 2;
    constexpr int PIX = NIMG * (RS + 2) * PH;
    constexpr int M   = NIMG * RS * HW;
    constexpr int MT  = M / 16;
    constexpr int MW  = MT / 4;
    constexpr int KC  = CI / 32;
    constexpr int NSTEP = 9 * KC;
    constexpr int SL  = HW / RS;
    constexpr int NC8 = CI / 8;

    __shared__ __align__(128) u16 s_in[PIX * CI];

    const int tid = threadIdx.x;
    const int g   = blockIdx.x;
    const int b0  = (g / SL) * NIMG;
    const int r0  = (g % SL) * RS;
    const int co0 = blockIdx.y * (NT * 16);

    constexpr int TOTC = PIX * NC8;
    for (int i = tid; i < TOTC; i += 256) {
        int c8 = i % NC8;
        int pp = i / NC8;
        int xx = pp % PH;
        int rr = pp / PH;
        int yy = rr % (RS + 2);
        int img = rr / (RS + 2);
        int gy = r0 + yy - 1, gx = xx - 1;
        uint4 v = {0u, 0u, 0u, 0u};
        if ((unsigned)gy < (unsigned)HW && (unsigned)gx < (unsigned)HW)
            v = *(const uint4*)(in + ((((size_t)(b0 + img) * HW + gy) * HW + gx) * CI + c8 * 8));
        int off = ((pp * CI + c8 * 8) * 2) ^ ((pp & 7) << 4);
        *(uint4*)((char*)s_in + off) = v;
    }
    __syncthreads();

    const int wv = tid >> 6, ln = tid & 63;
    const int l15 = ln & 15, lq = ln >> 4;

    int ppad[MW];
    #pragma unroll
    for (int mw = 0; mw < MW; ++mw) {
        int p = (wv * MW + mw) * 16 + l15;
        int img = p / (RS * HW);
        int rem = p % (RS * HW);
        int ly = rem / HW, lx = rem % HW;
        ppad[mw] = (img * (RS + 2) + ly + 1) * PH + lx + 1;
    }

    f32x4 acc[MW][NT] = {};

    // fragment-ordered weights: co-tile block = NSTEP steps x 512 elems
    const u16* wtile = wq + ((size_t)blockIdx.y * NT) * NSTEP * 512 + (ln << 3);

    #pragma unroll
    for (int tap = 0; tap < 9; ++tap) {
        const int dy = tap / 3 - 1, dx = tap % 3 - 1;
        #pragma unroll
        for (int cb = 0; cb < KC; ++cb) {
            short8 bf[NT];
            #pragma unroll
            for (int nt = 0; nt < NT; ++nt)
                bf[nt] = *(const short8*)(wtile + ((nt * NSTEP + tap * KC + cb) << 9));
            #pragma unroll
            for (int mw = 0; mw < MW; ++mw) {
                int pp = ppad[mw] + dy * PH + dx;
                int off = ((pp * CI + cb * 32 + lq * 8) * 2) ^ ((pp & 7) << 4);
                short8 af = *(const short8*)((const char*)s_in + off);
                #pragma unroll
                for (int nt = 0; nt < NT; ++nt)
                    acc[mw][nt] = __builtin_amdgcn_mfma_f32_16x16x32_bf16(
                        af, bf[nt], acc[mw][nt], 0, 0, 0);
            }
        }
    }

    #pragma unroll
    for (int nt = 0; nt < NT; ++nt) {
        float qb = lutq(bias[co0 + nt * 16 + l15]);
        #pragma unroll
        for (int mw = 0; mw < MW; ++mw) {
            #pragma unroll
            for (int r = 0; r < 4; ++r) {
                int p = (wv * MW + mw) * 16 + lq * 4 + r;
                int img = p / (RS * HW), rem = p % (RS * HW);
                int ly = rem / HW, lx = rem % HW;
                float v = lutq(fmaxf(acc[mw][nt][r] + qb, 0.f));
                out[(((size_t)(b0 + img) * HW + r0 + ly) * HW + lx) * CO + co0 + nt * 16 + l15] = f2b(v);
            }
        }
    }
}

// ---------------- maxpool 2x2 on NHWC bf16 ------------------------------------------
__device__ __forceinline__ u32 bmax2(u32 a, u32 b) {
    float m0 = fmaxf(b2f((u16)a), b2f((u16)b));
    float m1 = fmaxf(b2f((u16)(a >> 16)), b2f((u16)(b >> 16)));
    return (u32)f2b(m0) | ((u32)f2b(m1) << 16);
}

template<int C, int HIN>
__global__ __launch_bounds__(256) void pool_nhwc(
    const u16* __restrict__ in, u16* __restrict__ out)
{
    constexpr int HO = HIN / 2, NC8 = C / 8;
    constexpr int TOT = B_SZ * HO * HO * NC8;
    int i = blockIdx.x * 256 + threadIdx.x;
    if (i >= TOT) return;
    int c8 = i % NC8;
    int pp = i / NC8;
    int xo = pp % HO, yo = (pp / HO) % HO, b = pp / (HO * HO);
    const u16* base = in + (size_t)b * HIN * HIN * C + c8 * 8;
    auto ld = [&](int yy, int xxp) {
        return *(const uint4*)(base + ((size_t)yy * HIN + xxp) * C);
    };
    uint4 v0 = ld(2 * yo, 2 * xo), v1 = ld(2 * yo, 2 * xo + 1);
    uint4 v2 = ld(2 * yo + 1, 2 * xo), v3 = ld(2 * yo + 1, 2 * xo + 1);
    uint4 r;
    r.x = bmax2(bmax2(v0.x, v1.x), bmax2(v2.x, v3.x));
    r.y = bmax2(bmax2(v0.y, v1.y), bmax2(v2.y, v3.y));
    r.z = bmax2(bmax2(v0.z, v1.z), bmax2(v2.z, v3.z));
    r.w = bmax2(bmax2(v0.w, v1.w), bmax2(v2.w, v3.w));
    *(uint4*)(out + (((size_t)b * HO + yo) * HO + xo) * C + c8 * 8) = r;
}

// pool3: NHWC [512][8][8][128] -> NCHW-flat [512][2048] (matches reference reshape)
__global__ __launch_bounds__(256) void pool3_flat(
    const u16* __restrict__ in, u16* __restrict__ out)
{
    int i = blockIdx.x * 256 + threadIdx.x;
    if (i >= B_SZ * 2048) return;
    int b = i >> 11, r = i & 2047;
    int c = r >> 4, p = r & 15, yo = p >> 2, xo = p & 3;
    auto at = [&](int dy, int dx) {
        return b2f(in[(((size_t)b * 8 + 2 * yo + dy) * 8 + 2 * xo + dx) * 128 + c]);
    };
    float m = fmaxf(fmaxf(at(0, 0), at(0, 1)), fmaxf(at(1, 0), at(1, 1)));
    out[i] = f2b(m);
}

// ---------------- FC via MFMA, split-K: partials fp32 (exact) -----------------------
template<int N, int K, int SK>
__global__ __launch_bounds__(256) void fc_splitk(
    const u16* __restrict__ x, const u16* __restrict__ wq, float* __restrict__ part)
{
    constexpr int KCH = K / SK;
    const int tid = threadIdx.x, wv = tid >> 6, ln = tid & 63;
    const int l15 = ln & 15, lq = ln >> 4;
    const int m0 = blockIdx.x * 128, n0 = blockIdx.y * 128;
    const int kb = blockIdx.z * KCH;
    const int mq = (wv >> 1) * 4, nq = (wv & 1) * 4;
    f32x4 acc[4][4] = {};
    const u16* xr[4];
    const u16* wt[4];
    #pragma unroll
    for (int t = 0; t < 4; ++t) {
        xr[t] = x  + (size_t)(m0 + (mq + t) * 16 + l15) * K + kb + lq * 8;
        wt[t] = wq + (size_t)((n0 >> 4) + nq + t) * (K / 32) * 512 + (ln << 3);
    }
    for (int k0 = 0; k0 < KCH; k0 += 32) {
        const int s = (kb + k0) >> 5;
        short8 a[4], b[4];
        #pragma unroll
        for (int t = 0; t < 4; ++t) {
            a[t] = *(const short8*)(xr[t] + k0);
            b[t] = *(const short8*)(wt[t] + (s << 9));
        }
        #pragma unroll
        for (int i = 0; i < 4; ++i)
            #pragma unroll
            for (int j = 0; j < 4; ++j)
                acc[i][j] = __builtin_amdgcn_mfma_f32_16x16x32_bf16(a[i], b[j], acc[i][j], 0, 0, 0);
    }
    float* pb = part + (size_t)blockIdx.z * (B_SZ * N);
    #pragma unroll
    for (int j = 0; j < 4; ++j) {
        int n = n0 + (nq + j) * 16 + l15;
        #pragma unroll
        for (int i = 0; i < 4; ++i)
            #pragma unroll
            for (int r = 0; r < 4; ++r) {
                int m = m0 + (mq + i) * 16 + lq * 4 + r;
                pb[(size_t)m * N + n] = acc[i][j][r];
            }
    }
}

// reduce SK partials + bias (+reluq) -> bf16
template<int N, int SK, bool RELUQ>
__global__ __launch_bounds__(256) void fc_reduce(
    const float* __restrict__ part, const float* __restrict__ bias, u16* __restrict__ out)
{
    int i = blockIdx.x * 256 + threadIdx.x;
    if (i >= B_SZ * N) return;
    float s = 0.f;
    #pragma unroll
    for (int k = 0; k < SK; ++k) s += part[(size_t)k * (B_SZ * N) + i];
    float v = s + lutq(bias[i % N]);
    if (RELUQ) v = lutq(fmaxf(v, 0.f));
    out[i] = f2b(v);
}

// ---------------- fc3 (128->10) + softmax, one wave per row -------------------------
__global__ __launch_bounds__(64) void fc3_softmax(
    const u16* __restrict__ x, const float* __restrict__ w,
    const float* __restrict__ bias, float* __restrict__ out)
{
    const int r = blockIdx.x;
    const int l = threadIdx.x;
    const float x0 = b2f(x[(size_t)r * 128 + l]);
    const float x1 = b2f(x[(size_t)r * 128 + 64 + l]);
    float d[10];
    #pragma unroll
    for (int o = 0; o < 10; ++o) {
        float p = x0 * lutq(w[o * 128 + l]) + x1 * lutq(w[o * 128 + 64 + l]);
        #pragma unroll
        for (int s = 32; s > 0; s >>= 1) p += __shfl_xor(p, s);
        d[o] = p + lutq(bias[o]);
    }
    float m = d[0];
    #pragma unroll
    for (int o = 1; o < 10; ++o) m = fmaxf(m, d[o]);
    float sum = 0.f;
    float e[10];
    #pragma unroll
    for (int o = 0; o < 10; ++o) { e[o] = expf(d[o] - m); sum += e[o]; }
    if (l < 10) {
        float num = 0.f;
        #pragma unroll
        for (int o = 0; o < 10; ++o) if (l == o) num = e[o];
        out[(size_t)r * 10 + l] = num / sum;
    }
}

extern "C" void kernel_launch(void* const* d_in, const int* in_sizes, int n_in,
                              void* d_out, int out_size, void* d_ws, size_t ws_size,
                              hipStream_t stream)
{
    const float* x   = (const float*)d_in[0];
    const float* w1  = (const float*)d_in[2];
    const float* b1  = (const float*)d_in[3];
    const float* w2  = (const float*)d_in[4];
    const float* b2  = (const float*)d_in[5];
    const float* w3  = (const float*)d_in[6];
    const float* b3  = (const float*)d_in[7];
    const float* w4  = (const float*)d_in[8];
    const float* b4  = (const float*)d_in[9];
    const float* w5  = (const float*)d_in[10];
    const float* b5  = (const float*)d_in[11];
    const float* w6  = (const float*)d_in[12];
    const float* b6  = (const float*)d_in[13];
    const float* fw1 = (const float*)d_in[14];
    const float* fb1 = (const float*)d_in[15];
    const float* fw2 = (const float*)d_in[16];
    const float* fb2 = (const float*)d_in[17];
    const float* fw3 = (const float*)d_in[18];
    const float* fb3 = (const float*)d_in[19];
    float* out = (float*)d_out;

    const size_t ACT = (size_t)B_SZ * 32 * 32 * 32;   // 16,777,216 bf16 elems
    u16* bufA = (u16*)d_ws;
    u16* bufB = bufA + ACT;
    u16* q2  = bufB + ACT;
    u16* q3  = q2 + 9216;
    u16* q4  = q3 + 18432;
    u16* q5  = q4 + 36864;
    u16* q6  = q5 + 73728;
    u16* qf1 = q6 + 147456;
    u16* qf2 = qf1 + (size_t)512 * 2048;
    u16* fc1out = bufA + (2u << 20);          // past fc1 input (512*2048 elems)

    dim3 blk(256);

    prep_weights<<<dim3((1399808 + 255) / 256), blk, 0, stream>>>(
        w2, w3, w4, w5, w6, fw1, fw2, q2, q3, q4, q5, q6, qf1, qf2);

    // conv1: fp32 -> NHWC bf16 [512,32,32,32]; x = img*4+quarter, y = co half
    conv1_mem<<<dim3(2048, 2), blk, 0, stream>>>(x, w1, b1, bufA);
    // conv2
    conv_mfma<32, 32, 32, 8, 1, 2><<<dim3(2048, 1), blk, 0, stream>>>(bufA, q2, b2, bufB);
    // pool1 -> [512,16,16,32]
    pool_nhwc<32, 32><<<dim3(2048), blk, 0, stream>>>(bufB, bufA);
    // conv3 -> [512,16,16,64]
    conv_mfma<16, 32, 64, 16, 1, 2><<<dim3(512, 2), blk, 0, stream>>>(bufA, q3, b3, bufB);
    // conv4
    conv_mfma<16, 64, 64, 16, 1, 2><<<dim3(512, 2), blk, 0, stream>>>(bufB, q4, b4, bufA);
    // pool2 -> [512,8,8,64]
    pool_nhwc<64, 16><<<dim3(1024), blk, 0, stream>>>(bufA, bufB);
    // conv5 -> [512,8,8,128]
    conv_mfma<8, 64, 128, 8, 2, 4><<<dim3(256, 2), blk, 0, stream>>>(bufB, q5, b5, bufA);
    // conv6
    conv_mfma<8, 128, 128, 8, 2, 4><<<dim3(256, 2), blk, 0, stream>>>(bufA, q6, b6, bufB);
    // pool3 -> NCHW-flat [512,2048] into bufA
    pool3_flat<<<dim3(4096), blk, 0, stream>>>(bufB, bufA);

    // fc1: [512,2048]->[512,512] split-K=16, partials fp32 in bufB (16 MB), exact
    fc_splitk<512, 2048, 16><<<dim3(4, 4, 16), blk, 0, stream>>>(bufA, qf1, (float*)bufB);
    fc_reduce<512, 16, true><<<dim3(1024), blk, 0, stream>>>((float*)bufB, fb1, fc1out);
    // fc2: [512,512]->[512,128] split-K=16 (1 iter/block), partials 1 MB
    fc_splitk<128, 512, 16><<<dim3(4, 1, 16), blk, 0, stream>>>(fc1out, qf2, (float*)bufB);
    fc_reduce<128, 16, true><<<dim3(256), blk, 0, stream>>>((float*)bufB, fb2, bufA);
    // fc3 + softmax
    fc3_softmax<<<dim3(512), dim3(64), 0, stream>>>(bufA, fw3, fb3, out);
}

// Round 7
// 142.444 us; speedup vs baseline: 10.1518x; 1.1625x over previous
//
#include <hip/hip_runtime.h>
#include <cstddef>

// CifarNetMem forward, MFMA path.
// Numerics: lutq values are k/16, |k|<=64 -> exact in bf16; conv/fc sums bounded
// by 2^23 -> fp32 accumulation is EXACT in any order => bf16-MFMA is bit-identical
// to the fp32 reference path for conv2..6 and fc1..3. conv1 stays fp32 (raw input)
// with a FIXED fma order (c outer, k inner) that must not change across rounds.
// R6->R7: (a) maxpools fused into conv2/conv4/conv6 epilogues via LDS (output slab
// is pool-self-contained; max of identical quantized values => bit-identical);
// conv6 emits NCHW-flat directly. (b) conv3/conv4 NT 2->4: each A-frag ds_read
// feeds 4 MFMAs (LDS pipe was limiting at NT=2), B traffic halves.

#define B_SZ 512
typedef unsigned short u16;
typedef unsigned int   u32;
typedef __attribute__((ext_vector_type(8))) short short8;   // 8 bf16 (4 VGPRs)
typedef __attribute__((ext_vector_type(4))) float f32x4;

__device__ __forceinline__ float lutq(float v) {
    float k = ceilf(v * 16.0f - 0.5f);
    k = fminf(64.0f, fmaxf(-64.0f, k));
    return k * 0.0625f;
}
__device__ __forceinline__ u16  f2b(float f) { return (u16)(__builtin_bit_cast(u32, f) >> 16); }
__device__ __forceinline__ float b2f(u16 u)  { return __builtin_bit_cast(float, (u32)u << 16); }

__device__ __forceinline__ u32 bmax2(u32 a, u32 b) {
    float m0 = fmaxf(b2f((u16)a), b2f((u16)b));
    float m1 = fmaxf(b2f((u16)(a >> 16)), b2f((u16)(b >> 16)));
    return (u32)f2b(m0) | ((u32)f2b(m1) << 16);
}

// ---------------- weight prep: quantize + bf16 + MFMA-fragment order ----------------
__device__ __forceinline__ void prep_conv_frag(const float* __restrict__ w, u16* __restrict__ q,
                                               int i, int CI) {
    int KC = CI >> 5, NSTEP = 9 * KC;
    int e = i & 7, t = i >> 3;
    int ln = t & 63, t2 = t >> 6;
    int step = t2 % NSTEP, co_tile = t2 / NSTEP;
    int tap = step / KC, cb = step - tap * KC;
    int co = co_tile * 16 + (ln & 15);
    int ci = cb * 32 + (ln >> 4) * 8 + e;
    q[i] = f2b(lutq(w[(co * CI + ci) * 9 + tap]));
}
__device__ __forceinline__ void prep_fc_frag(const float* __restrict__ w, u16* __restrict__ q,
                                             int i, int K) {
    int S = K >> 5;
    int e = i & 7, t = i >> 3;
    int ln = t & 63, t2 = t >> 6;
    int s = t2 % S, n_tile = t2 / S;
    int n = n_tile * 16 + (ln & 15);
    int k = s * 32 + (ln >> 4) * 8 + e;
    q[i] = f2b(lutq(w[(size_t)n * K + k]));
}

__global__ __launch_bounds__(256) void prep_weights(
    const float* __restrict__ w2, const float* __restrict__ w3, const float* __restrict__ w4,
    const float* __restrict__ w5, const float* __restrict__ w6,
    const float* __restrict__ fw1, const float* __restrict__ fw2,
    u16* q2, u16* q3, u16* q4, u16* q5, u16* q6, u16* qf1, u16* qf2)
{
    int i = blockIdx.x * 256 + threadIdx.x;
    if (i < 9216)                 { prep_conv_frag(w2, q2, i, 32);  }
    else if ((i -= 9216) < 18432) { prep_conv_frag(w3, q3, i, 32);  }
    else if ((i -= 18432) < 36864){ prep_conv_frag(w4, q4, i, 64);  }
    else if ((i -= 36864) < 73728){ prep_conv_frag(w5, q5, i, 64);  }
    else if ((i -= 73728) < 147456){ prep_conv_frag(w6, q6, i, 128); }
    else if ((i -= 147456) < 1048576){ prep_fc_frag(fw1, qf1, i, 2048); }
    else if ((i -= 1048576) < 65536) { prep_fc_frag(fw2, qf2, i, 512);  }
}

// ---------------- conv1: fp32 (raw input), FIXED fma order (c outer, k inner) -------
__global__ __launch_bounds__(256) void conv1_mem(
    const float* __restrict__ x, const float* __restrict__ w,
    const float* __restrict__ bias, u16* __restrict__ out)
{
    __shared__ float s_w[3][9][16];
    __shared__ float s_b[16];
    __shared__ float s_in[3][10][34];
    const int tid = threadIdx.x;
    const int co0 = blockIdx.y * 16;
    const int b   = blockIdx.x >> 2;          // image
    const int r0  = (blockIdx.x & 3) * 8;     // row quarter
    for (int i = tid; i < 432; i += 256) {
        int o = i % 16, k = (i / 16) % 9, c = i / 144;
        s_w[c][k][o] = lutq(w[((co0 + o) * 3 + c) * 9 + k]);
    }
    if (tid < 16) s_b[tid] = lutq(bias[co0 + tid]);
    for (int i = tid; i < 3 * 10 * 34; i += 256) {
        int xx = i % 34, yy = (i / 34) % 10, c = i / 340;
        int gy = r0 + yy - 1, gx = xx - 1;
        float v = 0.f;
        if ((unsigned)gy < 32u && (unsigned)gx < 32u)
            v = x[(((size_t)b * 3 + c) * 32 + gy) * 32 + gx];
        s_in[c][yy][xx] = v;
    }
    __syncthreads();
    const int y = tid >> 5, xx = tid & 31;    // local row 0..7, col 0..31
    float acc[16];
    #pragma unroll
    for (int o = 0; o < 16; ++o) acc[o] = 0.f;
    #pragma unroll
    for (int c = 0; c < 3; ++c) {
        #pragma unroll
        for (int k = 0; k < 9; ++k) {
            float iv = s_in[c][y + k / 3][xx + k % 3];
            #pragma unroll
            for (int o = 0; o < 16; ++o) acc[o] = fmaf(iv, s_w[c][k][o], acc[o]);
        }
    }
    u32 u[8];
    #pragma unroll
    for (int j = 0; j < 8; ++j) {
        float v0 = lutq(fmaxf(acc[2 * j]     + s_b[2 * j],     0.f));
        float v1 = lutq(fmaxf(acc[2 * j + 1] + s_b[2 * j + 1], 0.f));
        u[j] = (u32)f2b(v0) | ((u32)f2b(v1) << 16);
    }
    const int p = (b << 10) + ((r0 + y) << 5) + xx;   // b*1024 + row*32 + col
    u32* o4 = (u32*)(out + (size_t)p * 32 + co0);
    #pragma unroll
    for (int j = 0; j < 8; ++j) o4[j] = u[j];
}

// ---------------- MFMA implicit-GEMM conv: NHWC bf16 in, optional fused pool --------
// POOL: 0 = plain NHWC out; 1 = 2x2-maxpooled NHWC out; 2 = 2x2-maxpooled NCHW-flat.
template<int HW, int CI, int CO, int RS, int NIMG, int NT, int POOL = 0>
__global__ __launch_bounds__(256) void conv_mfma(
    const u16* __restrict__ in,    // [B][HW][HW][CI]
    const u16* __restrict__ wq,    // fragment-ordered (see prep)
    const float* __restrict__ bias,
    u16* __restrict__ out)
{
    constexpr int PH  = HW + 2;
    constexpr int PIX = NIMG * (RS + 2) * PH;
    constexpr int M   = NIMG * RS * HW;
    constexpr int MT  = M / 16;
    constexpr int MW  = MT / 4;
    constexpr int KC  = CI / 32;
    constexpr int NSTEP = 9 * KC;
    constexpr int SL  = HW / RS;
    constexpr int NC8 = CI / 8;
    constexpr int NTC = NT * 16;

    __shared__ __align__(128) u16 s_in[PIX * CI];

    const int tid = threadIdx.x;
    const int g   = blockIdx.x;
    const int b0  = (g / SL) * NIMG;
    const int r0  = (g % SL) * RS;
    const int co0 = blockIdx.y * NTC;

    constexpr int TOTC = PIX * NC8;
    for (int i = tid; i < TOTC; i += 256) {
        int c8 = i % NC8;
        int pp = i / NC8;
        int xx = pp % PH;
        int rr = pp / PH;
        int yy = rr % (RS + 2);
        int img = rr / (RS + 2);
        int gy = r0 + yy - 1, gx = xx - 1;
        uint4 v = {0u, 0u, 0u, 0u};
        if ((unsigned)gy < (unsigned)HW && (unsigned)gx < (unsigned)HW)
            v = *(const uint4*)(in + ((((size_t)(b0 + img) * HW + gy) * HW + gx) * CI + c8 * 8));
        int off = ((pp * CI + c8 * 8) * 2) ^ ((pp & 7) << 4);
        *(uint4*)((char*)s_in + off) = v;
    }
    __syncthreads();

    const int wv = tid >> 6, ln = tid & 63;
    const int l15 = ln & 15, lq = ln >> 4;

    int ppad[MW];
    #pragma unroll
    for (int mw = 0; mw < MW; ++mw) {
        int p = (wv * MW + mw) * 16 + l15;
        int img = p / (RS * HW);
        int rem = p % (RS * HW);
        int ly = rem / HW, lx = rem % HW;
        ppad[mw] = (img * (RS + 2) + ly + 1) * PH + lx + 1;
    }

    f32x4 acc[MW][NT] = {};

    // fragment-ordered weights: co-tile block = NSTEP steps x 512 elems
    const u16* wtile = wq + ((size_t)blockIdx.y * NT) * NSTEP * 512 + (ln << 3);

    #pragma unroll
    for (int tap = 0; tap < 9; ++tap) {
        const int dy = tap / 3 - 1, dx = tap % 3 - 1;
        #pragma unroll
        for (int cb = 0; cb < KC; ++cb) {
            short8 bf[NT];
            #pragma unroll
            for (int nt = 0; nt < NT; ++nt)
                bf[nt] = *(const short8*)(wtile + ((nt * NSTEP + tap * KC + cb) << 9));
            #pragma unroll
            for (int mw = 0; mw < MW; ++mw) {
                int pp = ppad[mw] + dy * PH + dx;
                int off = ((pp * CI + cb * 32 + lq * 8) * 2) ^ ((pp & 7) << 4);
                short8 af = *(const short8*)((const char*)s_in + off);
                #pragma unroll
                for (int nt = 0; nt < NT; ++nt)
                    acc[mw][nt] = __builtin_amdgcn_mfma_f32_16x16x32_bf16(
                        af, bf[nt], acc[mw][nt], 0, 0, 0);
            }
        }
    }

    if constexpr (POOL == 0) {
        #pragma unroll
        for (int nt = 0; nt < NT; ++nt) {
            float qb = lutq(bias[co0 + nt * 16 + l15]);
            #pragma unroll
            for (int mw = 0; mw < MW; ++mw) {
                #pragma unroll
                for (int r = 0; r < 4; ++r) {
                    int p = (wv * MW + mw) * 16 + lq * 4 + r;
                    int img = p / (RS * HW), rem = p % (RS * HW);
                    int ly = rem / HW, lx = rem % HW;
                    float v = lutq(fmaxf(acc[mw][nt][r] + qb, 0.f));
                    out[(((size_t)(b0 + img) * HW + r0 + ly) * HW + lx) * CO + co0 + nt * 16 + l15] = f2b(v);
                }
            }
        }
    } else {
        // write quantized outputs to LDS (alias s_in after barrier), then 2x2 maxpool
        __syncthreads();
        u16* s_out = s_in;
        #pragma unroll
        for (int nt = 0; nt < NT; ++nt) {
            float qb = lutq(bias[co0 + nt * 16 + l15]);
            #pragma unroll
            for (int mw = 0; mw < MW; ++mw) {
                #pragma unroll
                for (int r = 0; r < 4; ++r) {
                    int p = (wv * MW + mw) * 16 + lq * 4 + r;
                    float v = lutq(fmaxf(acc[mw][nt][r] + qb, 0.f));
                    s_out[p * NTC + nt * 16 + l15] = f2b(v);
                }
            }
        }
        __syncthreads();
        constexpr int PR = RS / 2, PC = HW / 2, HOW = HW / 2;
        constexpr int OCT = NIMG * PR * PC * (NTC / 8);
        for (int idx = tid; idx < OCT; idx += 256) {
            int c8 = idx % (NTC / 8);
            int pp = idx / (NTC / 8);
            int xo = pp % PC, yo = (pp / PC) % PR, img = pp / (PC * PR);
            int pb = (img * RS + 2 * yo) * HW + 2 * xo;
            uint4 v0 = *(const uint4*)(s_out + (pb)          * NTC + c8 * 8);
            uint4 v1 = *(const uint4*)(s_out + (pb + 1)      * NTC + c8 * 8);
            uint4 v2 = *(const uint4*)(s_out + (pb + HW)     * NTC + c8 * 8);
            uint4 v3 = *(const uint4*)(s_out + (pb + HW + 1) * NTC + c8 * 8);
            uint4 r;
            r.x = bmax2(bmax2(v0.x, v1.x), bmax2(v2.x, v3.x));
            r.y = bmax2(bmax2(v0.y, v1.y), bmax2(v2.y, v3.y));
            r.z = bmax2(bmax2(v0.z, v1.z), bmax2(v2.z, v3.z));
            r.w = bmax2(bmax2(v0.w, v1.w), bmax2(v2.w, v3.w));
            if constexpr (POOL == 1) {
                *(uint4*)(out + ((((size_t)(b0 + img) * HOW + (r0 >> 1) + yo) * HOW + xo) * CO
                                 + co0 + c8 * 8)) = r;
            } else {
                const u16* rv = (const u16*)&r;
                #pragma unroll
                for (int j = 0; j < 8; ++j)
                    out[((size_t)(b0 + img) * CO + co0 + c8 * 8 + j) * (PR * PC) + yo * PC + xo] = rv[j];
            }
        }
    }
}

// ---------------- FC via MFMA, split-K: partials fp32 (exact) -----------------------
template<int N, int K, int SK>
__global__ __launch_bounds__(256) void fc_splitk(
    const u16* __restrict__ x, const u16* __restrict__ wq, float* __restrict__ part)
{
    constexpr int KCH = K / SK;
    const int tid = threadIdx.x, wv = tid >> 6, ln = tid & 63;
    const int l15 = ln & 15, lq = ln >> 4;
    const int m0 = blockIdx.x * 128, n0 = blockIdx.y * 128;
    const int kb = blockIdx.z * KCH;
    const int mq = (wv >> 1) * 4, nq = (wv & 1) * 4;
    f32x4 acc[4][4] = {};
    const u16* xr[4];
    const u16* wt[4];
    #pragma unroll
    for (int t = 0; t < 4; ++t) {
        xr[t] = x  + (size_t)(m0 + (mq + t) * 16 + l15) * K + kb + lq * 8;
        wt[t] = wq + (size_t)((n0 >> 4) + nq + t) * (K / 32) * 512 + (ln << 3);
    }
    for (int k0 = 0; k0 < KCH; k0 += 32) {
        const int s = (kb + k0) >> 5;
        short8 a[4], b[4];
        #pragma unroll
        for (int t = 0; t < 4; ++t) {
            a[t] = *(const short8*)(xr[t] + k0);
            b[t] = *(const short8*)(wt[t] + (s << 9));
        }
        #pragma unroll
        for (int i = 0; i < 4; ++i)
            #pragma unroll
            for (int j = 0; j < 4; ++j)
                acc[i][j] = __builtin_amdgcn_mfma_f32_16x16x32_bf16(a[i], b[j], acc[i][j], 0, 0, 0);
    }
    float* pb = part + (size_t)blockIdx.z * (B_SZ * N);
    #pragma unroll
    for (int j = 0; j < 4; ++j) {
        int n = n0 + (nq + j) * 16 + l15;
        #pragma unroll
        for (int i = 0; i < 4; ++i)
            #pragma unroll
            for (int r = 0; r < 4; ++r) {
                int m = m0 + (mq + i) * 16 + lq * 4 + r;
                pb[(size_t)m * N + n] = acc[i][j][r];
            }
    }
}

// reduce SK partials + bias (+reluq) -> bf16
template<int N, int SK, bool RELUQ>
__global__ __launch_bounds__(256) void fc_reduce(
    const float* __restrict__ part, const float* __restrict__ bias, u16* __restrict__ out)
{
    int i = blockIdx.x * 256 + threadIdx.x;
    if (i >= B_SZ * N) return;
    float s = 0.f;
    #pragma unroll
    for (int k = 0; k < SK; ++k) s += part[(size_t)k * (B_SZ * N) + i];
    float v = s + lutq(bias[i % N]);
    if (RELUQ) v = lutq(fmaxf(v, 0.f));
    out[i] = f2b(v);
}

// ---------------- fc3 (128->10) + softmax, one wave per row -------------------------
__global__ __launch_bounds__(64) void fc3_softmax(
    const u16* __restrict__ x, const float* __restrict__ w,
    const float* __restrict__ bias, float* __restrict__ out)
{
    const int r = blockIdx.x;
    const int l = threadIdx.x;
    const float x0 = b2f(x[(size_t)r * 128 + l]);
    const float x1 = b2f(x[(size_t)r * 128 + 64 + l]);
    float d[10];
    #pragma unroll
    for (int o = 0; o < 10; ++o) {
        float p = x0 * lutq(w[o * 128 + l]) + x1 * lutq(w[o * 128 + 64 + l]);
        #pragma unroll
        for (int s = 32; s > 0; s >>= 1) p += __shfl_xor(p, s);
        d[o] = p + lutq(bias[o]);
    }
    float m = d[0];
    #pragma unroll
    for (int o = 1; o < 10; ++o) m = fmaxf(m, d[o]);
    float sum = 0.f;
    float e[10];
    #pragma unroll
    for (int o = 0; o < 10; ++o) { e[o] = expf(d[o] - m); sum += e[o]; }
    if (l < 10) {
        float num = 0.f;
        #pragma unroll
        for (int o = 0; o < 10; ++o) if (l == o) num = e[o];
        out[(size_t)r * 10 + l] = num / sum;
    }
}

extern "C" void kernel_launch(void* const* d_in, const int* in_sizes, int n_in,
                              void* d_out, int out_size, void* d_ws, size_t ws_size,
                              hipStream_t stream)
{
    const float* x   = (const float*)d_in[0];
    const float* w1  = (const float*)d_in[2];
    const float* b1  = (const float*)d_in[3];
    const float* w2  = (const float*)d_in[4];
    const float* b2  = (const float*)d_in[5];
    const float* w3  = (const float*)d_in[6];
    const float* b3  = (const float*)d_in[7];
    const float* w4  = (const float*)d_in[8];
    const float* b4  = (const float*)d_in[9];
    const float* w5  = (const float*)d_in[10];
    const float* b5  = (const float*)d_in[11];
    const float* w6  = (const float*)d_in[12];
    const float* b6  = (const float*)d_in[13];
    const float* fw1 = (const float*)d_in[14];
    const float* fb1 = (const float*)d_in[15];
    const float* fw2 = (const float*)d_in[16];
    const float* fb2 = (const float*)d_in[17];
    const float* fw3 = (const float*)d_in[18];
    const float* fb3 = (const float*)d_in[19];
    float* out = (float*)d_out;

    const size_t ACT = (size_t)B_SZ * 32 * 32 * 32;   // 16,777,216 elems
    u16* bufA = (u16*)d_ws;
    u16* bufB = bufA + ACT;
    u16* q2  = bufB + ACT;
    u16* q3  = q2 + 9216;
    u16* q4  = q3 + 18432;
    u16* q5  = q4 + 36864;
    u16* q6  = q5 + 73728;
    u16* qf1 = q6 + 147456;
    u16* qf2 = qf1 + (size_t)512 * 2048;
    u16* fc1out = bufB + (2u << 20);          // past fc1 input region (bufB[0..1M))
    u16* fc2out = bufB;                       // fc1 input dead by then

    dim3 blk(256);

    prep_weights<<<dim3((1399808 + 255) / 256), blk, 0, stream>>>(
        w2, w3, w4, w5, w6, fw1, fw2, q2, q3, q4, q5, q6, qf1, qf2);

    // conv1: fp32 -> NHWC bf16 [512,32,32,32]
    conv1_mem<<<dim3(2048, 2), blk, 0, stream>>>(x, w1, b1, bufA);
    // conv2 + pool1 -> [512,16,16,32]
    conv_mfma<32, 32, 32, 8, 1, 2, 1><<<dim3(2048, 1), blk, 0, stream>>>(bufA, q2, b2, bufB);
    // conv3 -> [512,16,16,64]
    conv_mfma<16, 32, 64, 16, 1, 4><<<dim3(512, 1), blk, 0, stream>>>(bufB, q3, b3, bufA);
    // conv4 + pool2 -> [512,8,8,64]
    conv_mfma<16, 64, 64, 16, 1, 4, 1><<<dim3(512, 1), blk, 0, stream>>>(bufA, q4, b4, bufB);
    // conv5 -> [512,8,8,128]
    conv_mfma<8, 64, 128, 8, 2, 4><<<dim3(256, 2), blk, 0, stream>>>(bufB, q5, b5, bufA);
    // conv6 + pool3 -> NCHW-flat [512,2048]
    conv_mfma<8, 128, 128, 8, 2, 4, 2><<<dim3(256, 2), blk, 0, stream>>>(bufA, q6, b6, bufB);

    // fc1: [512,2048]->[512,512] split-K=16, fp32 partials in bufA (16 MB), exact
    fc_splitk<512, 2048, 16><<<dim3(4, 4, 16), blk, 0, stream>>>(bufB, qf1, (float*)bufA);
    fc_reduce<512, 16, true><<<dim3(1024), blk, 0, stream>>>((float*)bufA, fb1, fc1out);
    // fc2: [512,512]->[512,128] split-K=16, partials 1 MB
    fc_splitk<128, 512, 16><<<dim3(4, 1, 16), blk, 0, stream>>>(fc1out, qf2, (float*)bufA);
    fc_reduce<128, 16, true><<<dim3(256), blk, 0, stream>>>((float*)bufA, fb2, fc2out);
    // fc3 + softmax
    fc3_softmax<<<dim3(512), dim3(64), 0, stream>>>(fc2out, fw3, fb3, out);
}

// Round 8
// 100.582 us; speedup vs baseline: 14.3769x; 1.4162x over previous
//
#include <hip/hip_runtime.h>
#include <cstddef>

// CifarNetMem forward, INT8-MFMA path.
// All LUT-quantized values are k/16, k in [-64,64] -> exact i8. Products k_a*k_w
// <= 4096, sums <= K*4096 << 2^31 -> i32 MFMA accumulation is EXACT. Requantize:
// lutq(relu(v)) == clamp((max(S + 16*kb, 0) + 7) >> 4, <=64) in pure ints (derived
// from the reference round-half-down tie rule) => bit-identical to the fp32 path.
// conv1 stays fp32 (raw input) with FIXED fma order (c outer, k inner); fc3 fp32.
// R7->R8: bf16 -> i8 everywhere else: mfma_i32_16x16x64_i8 (2x rate, K=64),
// activations/weights as i8 (half LDS + half fetch traffic). CI=32 convs pad
// K 288->320 with zero weights (exact).

#define B_SZ 512
typedef unsigned int u32;
typedef __attribute__((ext_vector_type(4))) int i32x4;

__device__ __forceinline__ float lutq(float v) {
    float k = ceilf(v * 16.0f - 0.5f);
    k = fminf(64.0f, fmaxf(-64.0f, k));
    return k * 0.0625f;
}
// integer LUT index of a float weight/bias
__device__ __forceinline__ int kq(float x) {
    float kf = ceilf(x * 16.0f - 0.5f);
    kf = fminf(64.0f, fmaxf(-64.0f, kf));
    return (int)kf;
}
// unsigned bytewise max (activations are 0..64)
__device__ __forceinline__ u32 bmax4u(u32 a, u32 b) {
    u32 r = 0;
    #pragma unroll
    for (int j = 0; j < 4; ++j) {
        u32 x = (a >> (8 * j)) & 255u, y = (b >> (8 * j)) & 255u;
        r |= (x > y ? x : y) << (8 * j);
    }
    return r;
}

// ---------------- weight prep: quantize to i8 + MFMA-fragment order -----------------
// conv frag: i = ((co_tile*NSTEP + s)*64 + ln)*16 + e, k = s*64+(ln>>4)*16+e,
//   tap = k/CI (>=9 -> zero pad), ci = k%CI, co = co_tile*16 + (ln&15). OIHW src.
__device__ __forceinline__ void prep_conv_frag(const float* __restrict__ w, char* __restrict__ q,
                                               int i, int CI) {
    int NSTEP = (9 * CI + 63) / 64;
    int e = i & 15, t = i >> 4;
    int ln = t & 63, t2 = t >> 6;
    int s = t2 % NSTEP, co_tile = t2 / NSTEP;
    int k = s * 64 + ((ln >> 4) << 4) + e;
    int tap = k / CI, ci = k % CI;
    int co = co_tile * 16 + (ln & 15);
    int val = 0;
    if (tap < 9) val = kq(w[(co * CI + ci) * 9 + tap]);
    q[i] = (char)val;
}
__device__ __forceinline__ void prep_fc_frag(const float* __restrict__ w, char* __restrict__ q,
                                             int i, int K) {
    int S = K >> 6;
    int e = i & 15, t = i >> 4;
    int ln = t & 63, t2 = t >> 6;
    int s = t2 % S, n_tile = t2 / S;
    int n = n_tile * 16 + (ln & 15);
    int k = s * 64 + ((ln >> 4) << 4) + e;
    q[i] = (char)kq(w[(size_t)n * K + k]);
}

__global__ __launch_bounds__(256) void prep_weights(
    const float* __restrict__ w2, const float* __restrict__ w3, const float* __restrict__ w4,
    const float* __restrict__ w5, const float* __restrict__ w6,
    const float* __restrict__ fw1, const float* __restrict__ fw2,
    char* q2, char* q3, char* q4, char* q5, char* q6, char* qf1, char* qf2)
{
    int i = blockIdx.x * 256 + threadIdx.x;
    if (i < 10240)                  { prep_conv_frag(w2, q2, i, 32);  }
    else if ((i -= 10240) < 20480)  { prep_conv_frag(w3, q3, i, 32);  }
    else if ((i -= 20480) < 36864)  { prep_conv_frag(w4, q4, i, 64);  }
    else if ((i -= 36864) < 73728)  { prep_conv_frag(w5, q5, i, 64);  }
    else if ((i -= 73728) < 147456) { prep_conv_frag(w6, q6, i, 128); }
    else if ((i -= 147456) < 1048576){ prep_fc_frag(fw1, qf1, i, 2048); }
    else if ((i -= 1048576) < 65536) { prep_fc_frag(fw2, qf2, i, 512);  }
}

// ---------------- conv1: fp32 (raw input), FIXED fma order (c outer, k inner) -------
__global__ __launch_bounds__(256) void conv1_mem(
    const float* __restrict__ x, const float* __restrict__ w,
    const float* __restrict__ bias, char* __restrict__ out)
{
    __shared__ float s_w[3][9][16];
    __shared__ float s_b[16];
    __shared__ float s_in[3][10][34];
    const int tid = threadIdx.x;
    const int co0 = blockIdx.y * 16;
    const int b   = blockIdx.x >> 2;          // image
    const int r0  = (blockIdx.x & 3) * 8;     // row quarter
    for (int i = tid; i < 432; i += 256) {
        int o = i % 16, k = (i / 16) % 9, c = i / 144;
        s_w[c][k][o] = lutq(w[((co0 + o) * 3 + c) * 9 + k]);
    }
    if (tid < 16) s_b[tid] = lutq(bias[co0 + tid]);
    for (int i = tid; i < 3 * 10 * 34; i += 256) {
        int xx = i % 34, yy = (i / 34) % 10, c = i / 340;
        int gy = r0 + yy - 1, gx = xx - 1;
        float v = 0.f;
        if ((unsigned)gy < 32u && (unsigned)gx < 32u)
            v = x[(((size_t)b * 3 + c) * 32 + gy) * 32 + gx];
        s_in[c][yy][xx] = v;
    }
    __syncthreads();
    const int y = tid >> 5, xx = tid & 31;    // local row 0..7, col 0..31
    float acc[16];
    #pragma unroll
    for (int o = 0; o < 16; ++o) acc[o] = 0.f;
    #pragma unroll
    for (int c = 0; c < 3; ++c) {
        #pragma unroll
        for (int k = 0; k < 9; ++k) {
            float iv = s_in[c][y + k / 3][xx + k % 3];
            #pragma unroll
            for (int o = 0; o < 16; ++o) acc[o] = fmaf(iv, s_w[c][k][o], acc[o]);
        }
    }
    u32 u[8];
    #pragma unroll
    for (int j = 0; j < 8; ++j) {
        u32 p = 0;
        #pragma unroll
        for (int q = 0; q < 4; ++q) {
            float v = fmaxf(acc[4 * j + q] + s_b[4 * j + q], 0.f);
            int kk = (int)ceilf(v * 16.0f - 0.5f);
            kk = kk > 64 ? 64 : kk;
            p |= ((u32)kk & 255u) << (8 * q);
        }
        u[j] = p;
    }
    const int p = (b << 10) + ((r0 + y) << 5) + xx;   // b*1024 + row*32 + col
    u32* o4 = (u32*)(out + (size_t)p * 32 + co0 * 2); // wait co0*? see below
    // NOTE: 32 channels per pixel, 1 byte each; co0 in {0,16} -> byte offset co0
    o4 = (u32*)(out + (size_t)p * 32 + co0);
    #pragma unroll
    for (int j = 0; j < 4; ++j) o4[j] = u[j + 0];
    // 16 channels = 16 bytes = 4 u32
}

// ---------------- MFMA implicit-GEMM conv: NHWC i8 in, optional fused pool ----------
// POOL: 0 = plain NHWC; 1 = 2x2-maxpooled NHWC; 2 = 2x2-maxpooled NCHW-flat.
template<int HW, int CI, int CO, int RS, int NIMG, int NT, int POOL = 0>
__global__ __launch_bounds__(256) void conv_mfma(
    const char* __restrict__ in,   // [B][HW][HW][CI] i8
    const char* __restrict__ wq,   // fragment-ordered i8
    const float* __restrict__ bias,
    char* __restrict__ out)
{
    constexpr int PH  = HW + 2;
    constexpr int PIX = NIMG * (RS + 2) * PH;
    constexpr int M   = NIMG * RS * HW;
    constexpr int MT  = M / 16;
    constexpr int MW  = MT / 4;
    constexpr int NSTEP = (9 * CI + 63) / 64;
    constexpr int SL  = HW / RS;
    constexpr int NC16 = CI / 16;
    constexpr int NTC = NT * 16;

    __shared__ __align__(128) char s_in[PIX * CI];

    const int tid = threadIdx.x;
    const int g   = blockIdx.x;
    const int b0  = (g / SL) * NIMG;
    const int r0  = (g % SL) * RS;
    const int co0 = blockIdx.y * NTC;

    constexpr int TOTC = PIX * NC16;
    for (int i = tid; i < TOTC; i += 256) {
        int c16 = i % NC16;
        int pp  = i / NC16;
        int xx  = pp % PH;
        int rr  = pp / PH;
        int yy  = rr % (RS + 2);
        int img = rr / (RS + 2);
        int gy = r0 + yy - 1, gx = xx - 1;
        uint4 v = {0u, 0u, 0u, 0u};
        if ((unsigned)gy < (unsigned)HW && (unsigned)gx < (unsigned)HW)
            v = *(const uint4*)(in + ((((size_t)(b0 + img) * HW + gy) * HW + gx) * CI + c16 * 16));
        int off = (pp * CI + c16 * 16) ^ ((pp & 7) << 4);
        *(uint4*)(s_in + off) = v;
    }
    __syncthreads();

    const int wv = tid >> 6, ln = tid & 63;
    const int l15 = ln & 15, lq = ln >> 4;

    int ppad[MW];
    #pragma unroll
    for (int mw = 0; mw < MW; ++mw) {
        int p = (wv * MW + mw) * 16 + l15;
        int img = p / (RS * HW);
        int rem = p % (RS * HW);
        int ly = rem / HW, lx = rem % HW;
        ppad[mw] = (img * (RS + 2) + ly + 1) * PH + lx + 1;
    }

    i32x4 acc[MW][NT] = {};

    const char* wtile = wq + ((size_t)blockIdx.y * NT) * NSTEP * 1024 + (ln << 4);
    auto dp = [](int t) { return (t / 3 - 1) * PH + (t % 3 - 1); };

    #pragma unroll
    for (int s = 0; s < NSTEP; ++s) {
        i32x4 bf[NT];
        #pragma unroll
        for (int nt = 0; nt < NT; ++nt)
            bf[nt] = *(const i32x4*)(wtile + ((nt * NSTEP + s) << 10));
        int dd, ci0;
        if constexpr (CI == 32) {
            int d0 = dp(2 * s);
            int d1 = (2 * s + 1 < 9) ? dp(2 * s + 1) : 0;
            dd  = (lq & 2) ? d1 : d0;
            ci0 = (lq & 1) << 4;
        } else if constexpr (CI == 64) {
            dd  = dp(s);
            ci0 = lq << 4;
        } else {
            dd  = dp(s >> 1);
            ci0 = ((s & 1) << 6) + (lq << 4);
        }
        #pragma unroll
        for (int mw = 0; mw < MW; ++mw) {
            int pix = ppad[mw] + dd;
            int off = (pix * CI + ci0) ^ ((pix & 7) << 4);
            i32x4 af = *(const i32x4*)(s_in + off);
            #pragma unroll
            for (int nt = 0; nt < NT; ++nt)
                acc[mw][nt] = __builtin_amdgcn_mfma_i32_16x16x64_i8(af, bf[nt], acc[mw][nt], 0, 0, 0);
        }
    }

    if constexpr (POOL == 0) {
        #pragma unroll
        for (int nt = 0; nt < NT; ++nt) {
            int kb16 = 16 * kq(bias[co0 + nt * 16 + l15]);
            #pragma unroll
            for (int mw = 0; mw < MW; ++mw) {
                #pragma unroll
                for (int r = 0; r < 4; ++r) {
                    int p = (wv * MW + mw) * 16 + lq * 4 + r;
                    int img = p / (RS * HW), rem = p % (RS * HW);
                    int ly = rem / HW, lx = rem % HW;
                    int vv = acc[mw][nt][r] + kb16;
                    vv = vv > 0 ? vv : 0;
                    int kk = (vv + 7) >> 4;
                    kk = kk > 64 ? 64 : kk;
                    out[(((size_t)(b0 + img) * HW + r0 + ly) * HW + lx) * CO + co0 + nt * 16 + l15] = (char)kk;
                }
            }
        }
    } else {
        __syncthreads();
        char* s_out = s_in;
        #pragma unroll
        for (int nt = 0; nt < NT; ++nt) {
            int kb16 = 16 * kq(bias[co0 + nt * 16 + l15]);
            #pragma unroll
            for (int mw = 0; mw < MW; ++mw) {
                #pragma unroll
                for (int r = 0; r < 4; ++r) {
                    int p = (wv * MW + mw) * 16 + lq * 4 + r;
                    int vv = acc[mw][nt][r] + kb16;
                    vv = vv > 0 ? vv : 0;
                    int kk = (vv + 7) >> 4;
                    kk = kk > 64 ? 64 : kk;
                    s_out[p * NTC + nt * 16 + l15] = (char)kk;
                }
            }
        }
        __syncthreads();
        constexpr int PR = RS / 2, PC = HW / 2, HOW = HW / 2;
        constexpr int OCT = NIMG * PR * PC * (NTC / 16);
        for (int idx = tid; idx < OCT; idx += 256) {
            int c16 = idx % (NTC / 16);
            int pp  = idx / (NTC / 16);
            int xo = pp % PC, yo = (pp / PC) % PR, img = pp / (PC * PR);
            int pb = (img * RS + 2 * yo) * HW + 2 * xo;
            uint4 v0 = *(const uint4*)(s_out + (pb)          * NTC + c16 * 16);
            uint4 v1 = *(const uint4*)(s_out + (pb + 1)      * NTC + c16 * 16);
            uint4 v2 = *(const uint4*)(s_out + (pb + HW)     * NTC + c16 * 16);
            uint4 v3 = *(const uint4*)(s_out + (pb + HW + 1) * NTC + c16 * 16);
            uint4 r;
            r.x = bmax4u(bmax4u(v0.x, v1.x), bmax4u(v2.x, v3.x));
            r.y = bmax4u(bmax4u(v0.y, v1.y), bmax4u(v2.y, v3.y));
            r.z = bmax4u(bmax4u(v0.z, v1.z), bmax4u(v2.z, v3.z));
            r.w = bmax4u(bmax4u(v0.w, v1.w), bmax4u(v2.w, v3.w));
            if constexpr (POOL == 1) {
                *(uint4*)(out + ((((size_t)(b0 + img) * HOW + (r0 >> 1) + yo) * HOW + xo) * CO
                                 + co0 + c16 * 16)) = r;
            } else {
                const char* rv = (const char*)&r;
                #pragma unroll
                for (int j = 0; j < 16; ++j)
                    out[((size_t)(b0 + img) * CO + co0 + c16 * 16 + j) * (PR * PC) + yo * PC + xo] = rv[j];
            }
        }
    }
}

// ---------------- FC via i8 MFMA, split-K: i32 partials (exact) ---------------------
template<int N, int K, int SK>
__global__ __launch_bounds__(256) void fc_splitk(
    const char* __restrict__ x, const char* __restrict__ wq, int* __restrict__ part)
{
    constexpr int KCH = K / SK;
    const int tid = threadIdx.x, wv = tid >> 6, ln = tid & 63;
    const int l15 = ln & 15, lq = ln >> 4;
    const int m0 = blockIdx.x * 128, n0 = blockIdx.y * 128;
    const int kb = blockIdx.z * KCH;
    const int mq = (wv >> 1) * 4, nq = (wv & 1) * 4;
    i32x4 acc[4][4] = {};
    const char* xr[4];
    const char* wt[4];
    #pragma unroll
    for (int t = 0; t < 4; ++t) {
        xr[t] = x  + (size_t)(m0 + (mq + t) * 16 + l15) * K + kb + lq * 16;
        wt[t] = wq + (size_t)((n0 >> 4) + nq + t) * (K / 64) * 1024 + (ln << 4);
    }
    for (int k0 = 0; k0 < KCH; k0 += 64) {
        const int s = (kb + k0) >> 6;
        i32x4 a[4], b[4];
        #pragma unroll
        for (int t = 0; t < 4; ++t) {
            a[t] = *(const i32x4*)(xr[t] + k0);
            b[t] = *(const i32x4*)(wt[t] + (s << 10));
        }
        #pragma unroll
        for (int i = 0; i < 4; ++i)
            #pragma unroll
            for (int j = 0; j < 4; ++j)
                acc[i][j] = __builtin_amdgcn_mfma_i32_16x16x64_i8(a[i], b[j], acc[i][j], 0, 0, 0);
    }
    int* pb = part + (size_t)blockIdx.z * (B_SZ * N);
    #pragma unroll
    for (int j = 0; j < 4; ++j) {
        int n = n0 + (nq + j) * 16 + l15;
        #pragma unroll
        for (int i = 0; i < 4; ++i)
            #pragma unroll
            for (int r = 0; r < 4; ++r) {
                int m = m0 + (mq + i) * 16 + lq * 4 + r;
                pb[(size_t)m * N + n] = acc[i][j][r];
            }
    }
}

// reduce SK i32 partials + bias + reluq -> i8
template<int N, int SK>
__global__ __launch_bounds__(256) void fc_reduce(
    const int* __restrict__ part, const float* __restrict__ bias, char* __restrict__ out)
{
    int i = blockIdx.x * 256 + threadIdx.x;
    if (i >= B_SZ * N) return;
    int s = 0;
    #pragma unroll
    for (int k = 0; k < SK; ++k) s += part[(size_t)k * (B_SZ * N) + i];
    int vv = s + 16 * kq(bias[i % N]);
    vv = vv > 0 ? vv : 0;
    int kk = (vv + 7) >> 4;
    kk = kk > 64 ? 64 : kk;
    out[i] = (char)kk;
}

// ---------------- fc3 (128->10) + softmax, one wave per row -------------------------
__global__ __launch_bounds__(64) void fc3_softmax(
    const char* __restrict__ x, const float* __restrict__ w,
    const float* __restrict__ bias, float* __restrict__ out)
{
    const int r = blockIdx.x;
    const int l = threadIdx.x;
    const float x0 = 0.0625f * (float)x[(size_t)r * 128 + l];
    const float x1 = 0.0625f * (float)x[(size_t)r * 128 + 64 + l];
    float d[10];
    #pragma unroll
    for (int o = 0; o < 10; ++o) {
        float p = x0 * lutq(w[o * 128 + l]) + x1 * lutq(w[o * 128 + 64 + l]);
        #pragma unroll
        for (int s = 32; s > 0; s >>= 1) p += __shfl_xor(p, s);
        d[o] = p + lutq(bias[o]);
    }
    float m = d[0];
    #pragma unroll
    for (int o = 1; o < 10; ++o) m = fmaxf(m, d[o]);
    float sum = 0.f;
    float e[10];
    #pragma unroll
    for (int o = 0; o < 10; ++o) { e[o] = expf(d[o] - m); sum += e[o]; }
    if (l < 10) {
        float num = 0.f;
        #pragma unroll
        for (int o = 0; o < 10; ++o) if (l == o) num = e[o];
        out[(size_t)r * 10 + l] = num / sum;
    }
}

extern "C" void kernel_launch(void* const* d_in, const int* in_sizes, int n_in,
                              void* d_out, int out_size, void* d_ws, size_t ws_size,
                              hipStream_t stream)
{
    const float* x   = (const float*)d_in[0];
    const float* w1  = (const float*)d_in[2];
    const float* b1  = (const float*)d_in[3];
    const float* w2  = (const float*)d_in[4];
    const float* b2  = (const float*)d_in[5];
    const float* w3  = (const float*)d_in[6];
    const float* b3  = (const float*)d_in[7];
    const float* w4  = (const float*)d_in[8];
    const float* b4  = (const float*)d_in[9];
    const float* w5  = (const float*)d_in[10];
    const float* b5  = (const float*)d_in[11];
    const float* w6  = (const float*)d_in[12];
    const float* b6  = (const float*)d_in[13];
    const float* fw1 = (const float*)d_in[14];
    const float* fb1 = (const float*)d_in[15];
    const float* fw2 = (const float*)d_in[16];
    const float* fb2 = (const float*)d_in[17];
    const float* fw3 = (const float*)d_in[18];
    const float* fb3 = (const float*)d_in[19];
    float* out = (float*)d_out;

    char* bufA = (char*)d_ws;                 // 16 MiB activations
    char* bufB = bufA + (16u << 20);          // 16 MiB activations
    char* q2  = bufB + (16u << 20);
    char* q3  = q2 + 10240;
    char* q4  = q3 + 20480;
    char* q5  = q4 + 36864;
    char* q6  = q5 + 73728;
    char* qf1 = q6 + 147456;
    char* qf2 = qf1 + 1048576;
    int*  part = (int*)(qf2 + 65536);         // 16 MiB i32 partials
    char* fc1out = (char*)part + (16u << 20); // 256 KiB
    char* fc2out = fc1out + 262144;

    dim3 blk(256);

    prep_weights<<<dim3((1402880 + 255) / 256), blk, 0, stream>>>(
        w2, w3, w4, w5, w6, fw1, fw2, q2, q3, q4, q5, q6, qf1, qf2);

    // conv1: fp32 -> NHWC i8 [512,32,32,32]
    conv1_mem<<<dim3(2048, 2), blk, 0, stream>>>(x, w1, b1, bufA);
    // conv2 + pool1 -> [512,16,16,32]
    conv_mfma<32, 32, 32, 8, 1, 2, 1><<<dim3(2048, 1), blk, 0, stream>>>(bufA, q2, b2, bufB);
    // conv3 -> [512,16,16,64]
    conv_mfma<16, 32, 64, 16, 1, 4, 0><<<dim3(512, 1), blk, 0, stream>>>(bufB, q3, b3, bufA);
    // conv4 + pool2 -> [512,8,8,64]
    conv_mfma<16, 64, 64, 16, 1, 4, 1><<<dim3(512, 1), blk, 0, stream>>>(bufA, q4, b4, bufB);
    // conv5 -> [512,8,8,128]
    conv_mfma<8, 64, 128, 8, 2, 4, 0><<<dim3(256, 2), blk, 0, stream>>>(bufB, q5, b5, bufA);
    // conv6 + pool3 -> NCHW-flat i8 [512,2048]
    conv_mfma<8, 128, 128, 8, 2, 4, 2><<<dim3(256, 2), blk, 0, stream>>>(bufA, q6, b6, bufB);

    // fc1: [512,2048]->[512,512] split-K=16, i32 partials, exact
    fc_splitk<512, 2048, 16><<<dim3(4, 4, 16), blk, 0, stream>>>(bufB, qf1, part);
    fc_reduce<512, 16><<<dim3(1024), blk, 0, stream>>>(part, fb1, fc1out);
    // fc2: [512,512]->[512,128] split-K=8 (1 iter/block)
    fc_splitk<128, 512, 8><<<dim3(4, 1, 8), blk, 0, stream>>>(fc1out, qf2, part);
    fc_reduce<128, 8><<<dim3(256), blk, 0, stream>>>(part, fb2, fc2out);
    // fc3 + softmax (fp32, unchanged math)
    fc3_softmax<<<dim3(512), dim3(64), 0, stream>>>(fc2out, fw3, fb3, out);
}

// Round 9
// 97.618 us; speedup vs baseline: 14.8134x; 1.0304x over previous
//
#include <hip/hip_runtime.h>
#include <cstddef>

// CifarNetMem forward, INT8-MFMA path.
// All LUT-quantized values are k/16, k in [-64,64] -> exact i8. Products k_a*k_w
// <= 4096, sums <= K*4096 << 2^31 -> i32 MFMA accumulation is EXACT. Requantize:
// lutq(relu(v)) == clamp((max(S + 16*kb, 0) + 7) >> 4, <=64) in pure ints => bit-
// identical to the fp32 reference path. conv1 stays fp32 (raw input) with FIXED
// fma order (c outer, k inner); fc3 logits = (S + 16*kb)/256 exact fp32.
// R8->R9: (a) fc2+fc3+softmax fused into one fc_tail kernel (launches 12->10),
// (b) conv1 computes all 32 co per thread (grid y 2->1; spill-safe since input is
// LDS-staged), (c) conv6 epilogue emits fc1's A-matrix in MFMA fragment order ->
// fc1 A loads fully coalesced (was 16-way scattered).

#define B_SZ 512
typedef unsigned int u32;
typedef __attribute__((ext_vector_type(4))) int i32x4;

__device__ __forceinline__ float lutq(float v) {
    float k = ceilf(v * 16.0f - 0.5f);
    k = fminf(64.0f, fmaxf(-64.0f, k));
    return k * 0.0625f;
}
__device__ __forceinline__ int kq(float x) {
    float kf = ceilf(x * 16.0f - 0.5f);
    kf = fminf(64.0f, fmaxf(-64.0f, kf));
    return (int)kf;
}
__device__ __forceinline__ u32 bmax4u(u32 a, u32 b) {
    u32 r = 0;
    #pragma unroll
    for (int j = 0; j < 4; ++j) {
        u32 x = (a >> (8 * j)) & 255u, y = (b >> (8 * j)) & 255u;
        r |= (x > y ? x : y) << (8 * j);
    }
    return r;
}

// ---------------- weight prep: quantize to i8 + MFMA-fragment order -----------------
__device__ __forceinline__ void prep_conv_frag(const float* __restrict__ w, char* __restrict__ q,
                                               int i, int CI) {
    int NSTEP = (9 * CI + 63) / 64;
    int e = i & 15, t = i >> 4;
    int ln = t & 63, t2 = t >> 6;
    int s = t2 % NSTEP, co_tile = t2 / NSTEP;
    int k = s * 64 + ((ln >> 4) << 4) + e;
    int tap = k / CI, ci = k % CI;
    int co = co_tile * 16 + (ln & 15);
    int val = 0;
    if (tap < 9) val = kq(w[(co * CI + ci) * 9 + tap]);
    q[i] = (char)val;
}
__device__ __forceinline__ void prep_fc_frag(const float* __restrict__ w, char* __restrict__ q,
                                             int i, int K) {
    int S = K >> 6;
    int e = i & 15, t = i >> 4;
    int ln = t & 63, t2 = t >> 6;
    int s = t2 % S, n_tile = t2 / S;
    int n = n_tile * 16 + (ln & 15);
    int k = s * 64 + ((ln >> 4) << 4) + e;
    q[i] = (char)kq(w[(size_t)n * K + k]);
}

__global__ __launch_bounds__(256) void prep_weights(
    const float* __restrict__ w2, const float* __restrict__ w3, const float* __restrict__ w4,
    const float* __restrict__ w5, const float* __restrict__ w6,
    const float* __restrict__ fw1, const float* __restrict__ fw2,
    char* q2, char* q3, char* q4, char* q5, char* q6, char* qf1, char* qf2)
{
    int i = blockIdx.x * 256 + threadIdx.x;
    if (i < 10240)                  { prep_conv_frag(w2, q2, i, 32);  }
    else if ((i -= 10240) < 20480)  { prep_conv_frag(w3, q3, i, 32);  }
    else if ((i -= 20480) < 36864)  { prep_conv_frag(w4, q4, i, 64);  }
    else if ((i -= 36864) < 73728)  { prep_conv_frag(w5, q5, i, 64);  }
    else if ((i -= 73728) < 147456) { prep_conv_frag(w6, q6, i, 128); }
    else if ((i -= 147456) < 1048576){ prep_fc_frag(fw1, qf1, i, 2048); }
    else if ((i -= 1048576) < 65536) { prep_fc_frag(fw2, qf2, i, 512);  }
}

// ---------------- conv1: fp32 (raw input), FIXED fma order (c outer, k inner) -------
// All 32 output channels per thread (input LDS-staged -> no hoisted-load pressure).
__global__ __launch_bounds__(256) void conv1_mem(
    const float* __restrict__ x, const float* __restrict__ w,
    const float* __restrict__ bias, char* __restrict__ out)
{
    __shared__ float s_w[3][9][32];
    __shared__ float s_b[32];
    __shared__ float s_in[3][10][34];
    const int tid = threadIdx.x;
    const int b   = blockIdx.x >> 2;          // image
    const int r0  = (blockIdx.x & 3) * 8;     // row quarter
    for (int i = tid; i < 864; i += 256) {
        int o = i % 32, k = (i / 32) % 9, c = i / 288;
        s_w[c][k][o] = lutq(w[(o * 3 + c) * 9 + k]);
    }
    if (tid < 32) s_b[tid] = lutq(bias[tid]);
    for (int i = tid; i < 3 * 10 * 34; i += 256) {
        int xx = i % 34, yy = (i / 34) % 10, c = i / 340;
        int gy = r0 + yy - 1, gx = xx - 1;
        float v = 0.f;
        if ((unsigned)gy < 32u && (unsigned)gx < 32u)
            v = x[(((size_t)b * 3 + c) * 32 + gy) * 32 + gx];
        s_in[c][yy][xx] = v;
    }
    __syncthreads();
    const int y = tid >> 5, xx = tid & 31;
    float acc[32];
    #pragma unroll
    for (int o = 0; o < 32; ++o) acc[o] = 0.f;
    #pragma unroll
    for (int c = 0; c < 3; ++c) {
        #pragma unroll
        for (int k = 0; k < 9; ++k) {
            float iv = s_in[c][y + k / 3][xx + k % 3];
            #pragma unroll
            for (int o = 0; o < 32; ++o) acc[o] = fmaf(iv, s_w[c][k][o], acc[o]);
        }
    }
    u32 u[8];
    #pragma unroll
    for (int j = 0; j < 8; ++j) {
        u32 p = 0;
        #pragma unroll
        for (int q = 0; q < 4; ++q) {
            float v = fmaxf(acc[4 * j + q] + s_b[4 * j + q], 0.f);
            int kk = (int)ceilf(v * 16.0f - 0.5f);
            kk = kk > 64 ? 64 : kk;
            p |= ((u32)kk & 255u) << (8 * q);
        }
        u[j] = p;
    }
    const int p = (b << 10) + ((r0 + y) << 5) + xx;
    u32* o4 = (u32*)(out + (size_t)p * 32);
    #pragma unroll
    for (int j = 0; j < 8; ++j) o4[j] = u[j];
}

// ---------------- MFMA implicit-GEMM conv: NHWC i8 in, optional fused pool ----------
// POOL: 0 = plain NHWC; 1 = 2x2-maxpooled NHWC; 2 = 2x2-maxpooled fc1-FRAGMENT-A out.
template<int HW, int CI, int CO, int RS, int NIMG, int NT, int POOL = 0>
__global__ __launch_bounds__(256) void conv_mfma(
    const char* __restrict__ in,   // [B][HW][HW][CI] i8
    const char* __restrict__ wq,   // fragment-ordered i8
    const float* __restrict__ bias,
    char* __restrict__ out)
{
    constexpr int PH  = HW + 2;
    constexpr int PIX = NIMG * (RS + 2) * PH;
    constexpr int M   = NIMG * RS * HW;
    constexpr int MT  = M / 16;
    constexpr int MW  = MT / 4;
    constexpr int NSTEP = (9 * CI + 63) / 64;
    constexpr int SL  = HW / RS;
    constexpr int NC16 = CI / 16;
    constexpr int NTC = NT * 16;

    __shared__ __align__(128) char s_in[PIX * CI];

    const int tid = threadIdx.x;
    const int g   = blockIdx.x;
    const int b0  = (g / SL) * NIMG;
    const int r0  = (g % SL) * RS;
    const int co0 = blockIdx.y * NTC;

    constexpr int TOTC = PIX * NC16;
    for (int i = tid; i < TOTC; i += 256) {
        int c16 = i % NC16;
        int pp  = i / NC16;
        int xx  = pp % PH;
        int rr  = pp / PH;
        int yy  = rr % (RS + 2);
        int img = rr / (RS + 2);
        int gy = r0 + yy - 1, gx = xx - 1;
        uint4 v = {0u, 0u, 0u, 0u};
        if ((unsigned)gy < (unsigned)HW && (unsigned)gx < (unsigned)HW)
            v = *(const uint4*)(in + ((((size_t)(b0 + img) * HW + gy) * HW + gx) * CI + c16 * 16));
        int off = (pp * CI + c16 * 16) ^ ((pp & 7) << 4);
        *(uint4*)(s_in + off) = v;
    }
    __syncthreads();

    const int wv = tid >> 6, ln = tid & 63;
    const int l15 = ln & 15, lq = ln >> 4;

    int ppad[MW];
    #pragma unroll
    for (int mw = 0; mw < MW; ++mw) {
        int p = (wv * MW + mw) * 16 + l15;
        int img = p / (RS * HW);
        int rem = p % (RS * HW);
        int ly = rem / HW, lx = rem % HW;
        ppad[mw] = (img * (RS + 2) + ly + 1) * PH + lx + 1;
    }

    i32x4 acc[MW][NT] = {};

    const char* wtile = wq + ((size_t)blockIdx.y * NT) * NSTEP * 1024 + (ln << 4);
    auto dp = [](int t) { return (t / 3 - 1) * PH + (t % 3 - 1); };

    #pragma unroll
    for (int s = 0; s < NSTEP; ++s) {
        i32x4 bf[NT];
        #pragma unroll
        for (int nt = 0; nt < NT; ++nt)
            bf[nt] = *(const i32x4*)(wtile + ((nt * NSTEP + s) << 10));
        int dd, ci0;
        if constexpr (CI == 32) {
            int d0 = dp(2 * s);
            int d1 = (2 * s + 1 < 9) ? dp(2 * s + 1) : 0;
            dd  = (lq & 2) ? d1 : d0;
            ci0 = (lq & 1) << 4;
        } else if constexpr (CI == 64) {
            dd  = dp(s);
            ci0 = lq << 4;
        } else {
            dd  = dp(s >> 1);
            ci0 = ((s & 1) << 6) + (lq << 4);
        }
        #pragma unroll
        for (int mw = 0; mw < MW; ++mw) {
            int pix = ppad[mw] + dd;
            int off = (pix * CI + ci0) ^ ((pix & 7) << 4);
            i32x4 af = *(const i32x4*)(s_in + off);
            #pragma unroll
            for (int nt = 0; nt < NT; ++nt)
                acc[mw][nt] = __builtin_amdgcn_mfma_i32_16x16x64_i8(af, bf[nt], acc[mw][nt], 0, 0, 0);
        }
    }

    if constexpr (POOL == 0) {
        #pragma unroll
        for (int nt = 0; nt < NT; ++nt) {
            int kb16 = 16 * kq(bias[co0 + nt * 16 + l15]);
            #pragma unroll
            for (int mw = 0; mw < MW; ++mw) {
                #pragma unroll
                for (int r = 0; r < 4; ++r) {
                    int p = (wv * MW + mw) * 16 + lq * 4 + r;
                    int img = p / (RS * HW), rem = p % (RS * HW);
                    int ly = rem / HW, lx = rem % HW;
                    int vv = acc[mw][nt][r] + kb16;
                    vv = vv > 0 ? vv : 0;
                    int kk = (vv + 7) >> 4;
                    kk = kk > 64 ? 64 : kk;
                    out[(((size_t)(b0 + img) * HW + r0 + ly) * HW + lx) * CO + co0 + nt * 16 + l15] = (char)kk;
                }
            }
        }
    } else {
        __syncthreads();
        char* s_out = s_in;
        #pragma unroll
        for (int nt = 0; nt < NT; ++nt) {
            int kb16 = 16 * kq(bias[co0 + nt * 16 + l15]);
            #pragma unroll
            for (int mw = 0; mw < MW; ++mw) {
                #pragma unroll
                for (int r = 0; r < 4; ++r) {
                    int p = (wv * MW + mw) * 16 + lq * 4 + r;
                    int vv = acc[mw][nt][r] + kb16;
                    vv = vv > 0 ? vv : 0;
                    int kk = (vv + 7) >> 4;
                    kk = kk > 64 ? 64 : kk;
                    s_out[p * NTC + nt * 16 + l15] = (char)kk;
                }
            }
        }
        __syncthreads();
        constexpr int PR = RS / 2, PC = HW / 2, HOW = HW / 2;
        constexpr int OCT = NIMG * PR * PC * (NTC / 16);
        for (int idx = tid; idx < OCT; idx += 256) {
            int c16 = idx % (NTC / 16);
            int pp  = idx / (NTC / 16);
            int xo = pp % PC, yo = (pp / PC) % PR, img = pp / (PC * PR);
            int pb = (img * RS + 2 * yo) * HW + 2 * xo;
            uint4 v0 = *(const uint4*)(s_out + (pb)          * NTC + c16 * 16);
            uint4 v1 = *(const uint4*)(s_out + (pb + 1)      * NTC + c16 * 16);
            uint4 v2 = *(const uint4*)(s_out + (pb + HW)     * NTC + c16 * 16);
            uint4 v3 = *(const uint4*)(s_out + (pb + HW + 1) * NTC + c16 * 16);
            uint4 r;
            r.x = bmax4u(bmax4u(v0.x, v1.x), bmax4u(v2.x, v3.x));
            r.y = bmax4u(bmax4u(v0.y, v1.y), bmax4u(v2.y, v3.y));
            r.z = bmax4u(bmax4u(v0.z, v1.z), bmax4u(v2.z, v3.z));
            r.w = bmax4u(bmax4u(v0.w, v1.w), bmax4u(v2.w, v3.w));
            if constexpr (POOL == 1) {
                *(uint4*)(out + ((((size_t)(b0 + img) * HOW + (r0 >> 1) + yo) * HOW + xo) * CO
                                 + co0 + c16 * 16)) = r;
            } else {
                // fc1 fragment-A layout: K=2048, k = c*16 + yo*4 + xo, m = batch row.
                const char* rv = (const char*)&r;
                int m = b0 + img;
                #pragma unroll
                for (int j = 0; j < 16; ++j) {
                    int c = co0 + c16 * 16 + j;
                    int k = c * 16 + yo * 4 + xo;
                    int off = (((m >> 4) * 32 + (k >> 6)) << 10)
                            + ((((k >> 4) & 3) * 16 + (m & 15)) << 4) + (k & 15);
                    out[off] = rv[j];
                }
            }
        }
    }
}

// ---------------- fc1 via i8 MFMA, split-K, fragment-ordered A AND B ----------------
template<int N, int K, int SK>
__global__ __launch_bounds__(256) void fc1_splitk(
    const char* __restrict__ xa, const char* __restrict__ wq, int* __restrict__ part)
{
    constexpr int KCH = K / SK;
    constexpr int KS = K / 64;
    const int tid = threadIdx.x, wv = tid >> 6, ln = tid & 63;
    const int l15 = ln & 15, lq = ln >> 4;
    const int m0 = blockIdx.x * 128, n0 = blockIdx.y * 128;
    const int kb = blockIdx.z * KCH;
    const int mq = (wv >> 1) * 4, nq = (wv & 1) * 4;
    i32x4 acc[4][4] = {};
    const char* xr[4];
    const char* wt[4];
    #pragma unroll
    for (int t = 0; t < 4; ++t) {
        xr[t] = xa + (size_t)((m0 >> 4) + mq + t) * KS * 1024 + (ln << 4);
        wt[t] = wq + (size_t)((n0 >> 4) + nq + t) * KS * 1024 + (ln << 4);
    }
    for (int k0 = 0; k0 < KCH; k0 += 64) {
        const int s = (kb + k0) >> 6;
        i32x4 a[4], b[4];
        #pragma unroll
        for (int t = 0; t < 4; ++t) {
            a[t] = *(const i32x4*)(xr[t] + (s << 10));
            b[t] = *(const i32x4*)(wt[t] + (s << 10));
        }
        #pragma unroll
        for (int i = 0; i < 4; ++i)
            #pragma unroll
            for (int j = 0; j < 4; ++j)
                acc[i][j] = __builtin_amdgcn_mfma_i32_16x16x64_i8(a[i], b[j], acc[i][j], 0, 0, 0);
    }
    int* pb = part + (size_t)blockIdx.z * (B_SZ * N);
    #pragma unroll
    for (int j = 0; j < 4; ++j) {
        int n = n0 + (nq + j) * 16 + l15;
        #pragma unroll
        for (int i = 0; i < 4; ++i)
            #pragma unroll
            for (int r = 0; r < 4; ++r) {
                int m = m0 + (mq + i) * 16 + lq * 4 + r;
                pb[(size_t)m * N + n] = acc[i][j][r];
            }
    }
}

// reduce SK i32 partials + bias + reluq -> i8
template<int N, int SK>
__global__ __launch_bounds__(256) void fc_reduce(
    const int* __restrict__ part, const float* __restrict__ bias, char* __restrict__ out)
{
    int i = blockIdx.x * 256 + threadIdx.x;
    if (i >= B_SZ * N) return;
    int s = 0;
    #pragma unroll
    for (int k = 0; k < SK; ++k) s += part[(size_t)k * (B_SZ * N) + i];
    int vv = s + 16 * kq(bias[i % N]);
    vv = vv > 0 ? vv : 0;
    int kk = (vv + 7) >> 4;
    kk = kk > 64 ? 64 : kk;
    out[i] = (char)kk;
}

// ---------------- fc_tail: fc2 (MFMA) + requant + fc3 (int dot) + softmax -----------
// One block = 32 batch rows. x = fc1out [512][512] i8 row-major.
__global__ __launch_bounds__(256) void fc_tail(
    const char* __restrict__ x, const char* __restrict__ qf2,
    const float* __restrict__ fb2, const float* __restrict__ fw3,
    const float* __restrict__ fb3, float* __restrict__ out)
{
    __shared__ __align__(16) char sx[32 * 512];
    __shared__ __align__(16) char sy[32 * 128];
    __shared__ __align__(16) char sw3[10 * 128];
    __shared__ float sb3[10];
    __shared__ int sp[32][8][10];

    const int tid = threadIdx.x;
    const int m0 = blockIdx.x * 32;

    for (int idx = tid; idx < 1024; idx += 256) {
        int r = idx >> 5, c16 = idx & 31;
        uint4 v = *(const uint4*)(x + (size_t)(m0 + r) * 512 + c16 * 16);
        *(uint4*)(sx + ((r * 512 + c16 * 16) ^ ((r & 7) << 4))) = v;
    }
    for (int i = tid; i < 1280; i += 256) sw3[i] = (char)kq(fw3[i]);
    if (tid < 10) sb3[tid] = lutq(fb3[tid]);
    __syncthreads();

    // fc2: M=32, N=128, K=512. wave -> 1 m-tile x 4 n-tiles.
    const int wv = tid >> 6, ln = tid & 63, l15 = ln & 15, lq = ln >> 4;
    const int mt = wv >> 1, ntg = (wv & 1) * 4;
    i32x4 acc[4] = {};
    #pragma unroll
    for (int s = 0; s < 8; ++s) {
        int row = mt * 16 + l15;
        i32x4 a = *(const i32x4*)(sx + ((row * 512 + s * 64 + lq * 16) ^ ((row & 7) << 4)));
        #pragma unroll
        for (int nt = 0; nt < 4; ++nt) {
            i32x4 b = *(const i32x4*)(qf2 + (((ntg + nt) * 8 + s) << 10) + (ln << 4));
            acc[nt] = __builtin_amdgcn_mfma_i32_16x16x64_i8(a, b, acc[nt], 0, 0, 0);
        }
    }
    #pragma unroll
    for (int nt = 0; nt < 4; ++nt) {
        int n = (ntg + nt) * 16 + l15;
        int kb16 = 16 * kq(fb2[n]);
        #pragma unroll
        for (int r = 0; r < 4; ++r) {
            int row = mt * 16 + lq * 4 + r;
            int vv = acc[nt][r] + kb16;
            vv = vv > 0 ? vv : 0;
            int kk = (vv + 7) >> 4;
            kk = kk > 64 ? 64 : kk;
            sy[(row * 128 + n) ^ ((row & 7) << 4)] = (char)kk;
        }
    }
    __syncthreads();

    // fc3 partial dots: thread (r, g) covers k = g*16..g*16+15 for all 10 outputs
    {
        int r = tid >> 3, g = tid & 7;
        uint4 yv = *(const uint4*)(sy + ((r * 128 + g * 16) ^ ((r & 7) << 4)));
        const char* yb = (const char*)&yv;
        #pragma unroll
        for (int o = 0; o < 10; ++o) {
            uint4 wv4 = *(const uint4*)(sw3 + o * 128 + g * 16);
            const char* wb = (const char*)&wv4;
            int S = 0;
            #pragma unroll
            for (int e = 0; e < 16; ++e) S += (int)yb[e] * (int)wb[e];
            sp[r][g][o] = S;
        }
    }
    __syncthreads();

    if (tid < 32) {
        int r = tid;
        float d[10];
        #pragma unroll
        for (int o = 0; o < 10; ++o) {
            int S = 0;
            #pragma unroll
            for (int g = 0; g < 8; ++g) S += sp[r][g][o];
            d[o] = (float)S * 0.00390625f + sb3[o];   // exact: S/256 + kb/16
        }
        float m = d[0];
        #pragma unroll
        for (int o = 1; o < 10; ++o) m = fmaxf(m, d[o]);
        float e[10];
        float sum = 0.f;
        #pragma unroll
        for (int o = 0; o < 10; ++o) { e[o] = expf(d[o] - m); sum += e[o]; }
        #pragma unroll
        for (int o = 0; o < 10; ++o) out[(size_t)(m0 + r) * 10 + o] = e[o] / sum;
    }
}

extern "C" void kernel_launch(void* const* d_in, const int* in_sizes, int n_in,
                              void* d_out, int out_size, void* d_ws, size_t ws_size,
                              hipStream_t stream)
{
    const float* x   = (const float*)d_in[0];
    const float* w1  = (const float*)d_in[2];
    const float* b1  = (const float*)d_in[3];
    const float* w2  = (const float*)d_in[4];
    const float* b2  = (const float*)d_in[5];
    const float* w3  = (const float*)d_in[6];
    const float* b3  = (const float*)d_in[7];
    const float* w4  = (const float*)d_in[8];
    const float* b4  = (const float*)d_in[9];
    const float* w5  = (const float*)d_in[10];
    const float* b5  = (const float*)d_in[11];
    const float* w6  = (const float*)d_in[12];
    const float* b6  = (const float*)d_in[13];
    const float* fw1 = (const float*)d_in[14];
    const float* fb1 = (const float*)d_in[15];
    const float* fw2 = (const float*)d_in[16];
    const float* fb2 = (const float*)d_in[17];
    const float* fw3 = (const float*)d_in[18];
    const float* fb3 = (const float*)d_in[19];
    float* out = (float*)d_out;

    char* bufA = (char*)d_ws;                 // 16 MiB activations
    char* bufB = bufA + (16u << 20);          // 16 MiB activations
    char* q2  = bufB + (16u << 20);
    char* q3  = q2 + 10240;
    char* q4  = q3 + 20480;
    char* q5  = q4 + 36864;
    char* q6  = q5 + 73728;
    char* qf1 = q6 + 147456;
    char* qf2 = qf1 + 1048576;
    int*  part = (int*)(qf2 + 65536);         // 16 MiB i32 partials
    char* fc1out = (char*)part + (16u << 20); // 256 KiB
    char* fc1a   = fc1out + 262144;           // 1 MiB fragment-A for fc1

    dim3 blk(256);

    prep_weights<<<dim3((1402880 + 255) / 256), blk, 0, stream>>>(
        w2, w3, w4, w5, w6, fw1, fw2, q2, q3, q4, q5, q6, qf1, qf2);

    // conv1: fp32 -> NHWC i8 [512,32,32,32] (all 32 co per thread)
    conv1_mem<<<dim3(2048), blk, 0, stream>>>(x, w1, b1, bufA);
    // conv2 + pool1 -> [512,16,16,32]
    conv_mfma<32, 32, 32, 8, 1, 2, 1><<<dim3(2048, 1), blk, 0, stream>>>(bufA, q2, b2, bufB);
    // conv3 -> [512,16,16,64]
    conv_mfma<16, 32, 64, 16, 1, 4, 0><<<dim3(512, 1), blk, 0, stream>>>(bufB, q3, b3, bufA);
    // conv4 + pool2 -> [512,8,8,64]
    conv_mfma<16, 64, 64, 16, 1, 4, 1><<<dim3(512, 1), blk, 0, stream>>>(bufA, q4, b4, bufB);
    // conv5 -> [512,8,8,128]
    conv_mfma<8, 64, 128, 8, 2, 4, 0><<<dim3(256, 2), blk, 0, stream>>>(bufB, q5, b5, bufA);
    // conv6 + pool3 -> fc1 fragment-A [512 x 2048]
    conv_mfma<8, 128, 128, 8, 2, 4, 2><<<dim3(256, 2), blk, 0, stream>>>(bufA, q6, b6, fc1a);

    // fc1: [512,2048]->[512,512] split-K=16, i32 partials, exact
    fc1_splitk<512, 2048, 16><<<dim3(4, 4, 16), blk, 0, stream>>>(fc1a, qf1, part);
    fc_reduce<512, 16><<<dim3(1024), blk, 0, stream>>>(part, fb1, fc1out);
    // fc2 + fc3 + softmax fused
    fc_tail<<<dim3(16), blk, 0, stream>>>(fc1out, qf2, fb2, fw3, fb3, out);
}